// Round 1
// baseline (157.597 us; speedup 1.0000x reference)
//
#include <hip/hip_runtime.h>
#include <hip/hip_bf16.h>

typedef unsigned short u16;
typedef __attribute__((ext_vector_type(8))) short bf16x8;
typedef __attribute__((ext_vector_type(4))) float f32x4;

#define NE 8
#define NTOPK 4
#define NIN 768
#define NOUT 768
#define NB 16
#define NS 512
#define YSZ (NB * NS * NOUT)   // 6291456

// ---- workspace layout (bytes) ----
#define OFF_PART  0u           // 16*16*768 f32 partial sums  (786432 B used)
#define OFF_GATES 1048576u     // 16*8 f32
#define OFF_XBF   1049088u     // 16*512*768 bf16  = 12582912
#define OFF_MIN   13632000u    // 8*768*768 bf16   = 9437184
#define OFF_MOUT  23069184u    // 8*768*768 bf16
#define OFF_WD    32506368u    // 8*768*768 bf16
#define OFF_T1T   41943552u    // 8*768*768 bf16
#define OFF_RTW   51380736u    // 8*768*768 f32    = 18874368
#define OFF_EW    OFF_MIN      // 16*768*768 bf16 = 18874368, overlays Min+Mout (free after pass B)

__device__ __forceinline__ u16 f2bf(float f) {
  union { float f; unsigned u; } v; v.f = f;
  unsigned r = v.u + 0x7fffu + ((v.u >> 16) & 1u);
  return (u16)(r >> 16);
}

__device__ __forceinline__ void gload16(const void* g, void* l) {
  __builtin_amdgcn_global_load_lds(
      (const __attribute__((address_space(1))) unsigned int*)g,
      (__attribute__((address_space(3))) unsigned int*)l, 16, 0, 0);
}

__device__ __forceinline__ void storeC(float* p, float v) { *p = v; }
__device__ __forceinline__ void storeC(u16* p, float v) { *p = f2bf(v); }

// ---------------- K0: mean partials over S + x -> bf16 ----------------
// grid: 16 b * 16 sc = 256 blocks, 256 threads
__global__ __launch_bounds__(256) void k_xm(const float* __restrict__ x,
                                            float* __restrict__ part,
                                            u16* __restrict__ xbf) {
  int b = blockIdx.x >> 4;
  int sc = blockIdx.x & 15;
  int tid = threadIdx.x;
  float a0 = 0.f, a1 = 0.f, a2 = 0.f;
  int s0 = sc * 32;
  for (int s = s0; s < s0 + 32; ++s) {
    size_t ro = ((size_t)(b * NS + s)) * NIN;
    float v0 = x[ro + tid];
    float v1 = x[ro + tid + 256];
    float v2 = x[ro + tid + 512];
    a0 += v0; a1 += v1; a2 += v2;
    xbf[ro + tid]       = f2bf(v0);
    xbf[ro + tid + 256] = f2bf(v1);
    xbf[ro + tid + 512] = f2bf(v2);
  }
  size_t po = (size_t)(b * 16 + sc) * NIN;
  part[po + tid] = a0;
  part[po + tid + 256] = a1;
  part[po + tid + 512] = a2;
}

// ---------------- K1: gating (1 block) ----------------
__global__ __launch_bounds__(256) void k_gate(const float* __restrict__ part,
                                              const float* __restrict__ w_gate,
                                              float* __restrict__ gates_out,
                                              float* __restrict__ loss_out) {
  __shared__ float xm[NB * NIN];
  __shared__ float lg[NB * NE];
  __shared__ float gsh[NB * NE];
  int tid = threadIdx.x;
  for (int idx = tid; idx < NB * NIN; idx += 256) {
    int b = idx / NIN, i = idx % NIN;
    float s = 0.f;
    for (int sc = 0; sc < 16; ++sc) s += part[(size_t)(b * 16 + sc) * NIN + i];
    xm[idx] = s * (1.0f / (float)NS);
  }
  __syncthreads();
  if (tid < NB * NE) {
    int b = tid >> 3, e = tid & 7;
    float s = 0.f;
    for (int i = 0; i < NIN; ++i) s += xm[b * NIN + i] * w_gate[i * NE + e];
    lg[tid] = s;
  }
  __syncthreads();
  if (tid < NB) {
    int b = tid;
    float v[NE]; bool used[NE];
    for (int e = 0; e < NE; ++e) { v[e] = lg[b * NE + e]; used[e] = false; }
    int idxs[NTOPK]; float vals[NTOPK];
    for (int t = 0; t < NTOPK; ++t) {
      int best = 0; float bv = -3.4e38f;
      for (int e = 0; e < NE; ++e)
        if (!used[e] && v[e] > bv) { bv = v[e]; best = e; }
      used[best] = true; idxs[t] = best; vals[t] = bv;
    }
    float m = vals[0];
    float ex[NTOPK]; float se = 0.f;
    for (int t = 0; t < NTOPK; ++t) { ex[t] = expf(vals[t] - m); se += ex[t]; }
    for (int e = 0; e < NE; ++e) gsh[b * NE + e] = 0.f;
    for (int t = 0; t < NTOPK; ++t) gsh[b * NE + idxs[t]] = ex[t] / se;
  }
  __syncthreads();
  if (tid < NB * NE) gates_out[tid] = gsh[tid];
  if (tid == 0) {
    float imp[NE], ld[NE];
    for (int e = 0; e < NE; ++e) {
      float si = 0.f, sl = 0.f;
      for (int b = 0; b < NB; ++b) {
        float g = gsh[b * NE + e];
        si += g; sl += (g > 0.f) ? 1.f : 0.f;
      }
      imp[e] = si; ld[e] = sl;
    }
    float loss = 0.f;
    for (int which = 0; which < 2; ++which) {
      const float* a = which ? ld : imp;
      float mean = 0.f;
      for (int e = 0; e < NE; ++e) mean += a[e];
      mean *= (1.0f / NE);
      float var = 0.f;
      for (int e = 0; e < NE; ++e) { float d = a[e] - mean; var += d * d; }
      var *= (1.0f / (NE - 1));
      loss += var / (mean * mean + 1e-10f);
    }
    loss_out[0] = 0.01f * loss;
  }
}

// ---------------- K2: build Min, Mout (Kronecker), Wd = weight-res, all bf16 ----------------
// grid: (8, 48) blocks, 256 threads; each block does 16 rows
__global__ __launch_bounds__(256) void k_prep(const float* __restrict__ w,
                                              const float* __restrict__ res,
                                              const float* __restrict__ c1i,
                                              const float* __restrict__ c2i,
                                              const float* __restrict__ c1o,
                                              const float* __restrict__ c2o,
                                              u16* __restrict__ Min,
                                              u16* __restrict__ Mout,
                                              u16* __restrict__ Wd) {
  int e = blockIdx.x;
  int r0 = blockIdx.y * 16;
  int tid = threadIdx.x;
  for (int rr = 0; rr < 16; ++rr) {
    int r = r0 + rr;
    int r1 = r >> 5, r2 = r & 31;
    float ci1 = 0.f, ci2r = 0.f, co1 = 0.f, co2r = 0.f;
    size_t rowo = ((size_t)e * NIN + r) * NIN;
    for (int c = tid; c < NIN; c += 256) {
      int l = c >> 5, mm = c & 31;
      float a = c1i[(e * 24 + r1) * 24 + l] * c2i[(e * 32 + r2) * 32 + mm];
      float b = c1o[(e * 24 + r1) * 24 + l] * c2o[(e * 32 + r2) * 32 + mm];
      Min[rowo + c] = f2bf(a);
      Mout[rowo + c] = f2bf(b);
      Wd[rowo + c] = f2bf(w[rowo + c] - res[(size_t)r * NIN + c]);
    }
    (void)ci1; (void)ci2r; (void)co1; (void)co2r;
  }
}

// ---------------- GEMM: C[m][n] = sum_k A[m][k]*B[n][k], bf16 in, CT out ----------------
// 128x128 tile, BK=32, 256 threads (4 waves 2x2), global_load_lds staging
template <typename CT>
__global__ __launch_bounds__(256) void gemm_bt(const u16* __restrict__ A,
                                               const u16* __restrict__ B,
                                               CT* __restrict__ C,
                                               int M, int N, int Kd,
                                               size_t sA, size_t sB, size_t sC) {
  __shared__ u16 lA[128 * 32];
  __shared__ u16 lB[128 * 32];
  const int tid = threadIdx.x;
  const int lane = tid & 63;
  const int w = tid >> 6;
  const int wr = w >> 1, wc = w & 1;
  const int fr = lane & 15;
  const int kq = lane >> 4;
  const int m0 = blockIdx.x * 128;
  const int n0 = blockIdx.y * 128;
  const u16* Ab = A + (size_t)blockIdx.z * sA;
  const u16* Bb = B + (size_t)blockIdx.z * sB;

  f32x4 acc[4][4] = {};

  for (int k0 = 0; k0 < Kd; k0 += 32) {
#pragma unroll
    for (int q = 0; q < 2; ++q) {
      int ob = (w * 2 + q) * 1024 + lane * 16;  // byte offset in 8KB tile
      int row = ob >> 6;                        // 64B per row (32 bf16)
      int colb = ob & 63;
      gload16((const char*)Ab + ((size_t)(m0 + row) * Kd + k0) * 2 + colb,
              (char*)lA + ob);
      gload16((const char*)Bb + ((size_t)(n0 + row) * Kd + k0) * 2 + colb,
              (char*)lB + ob);
    }
    __syncthreads();
    bf16x8 aF[4], bF[4];
#pragma unroll
    for (int m = 0; m < 4; ++m)
      aF[m] = *(const bf16x8*)&lA[(wr * 64 + m * 16 + fr) * 32 + kq * 8];
#pragma unroll
    for (int n = 0; n < 4; ++n)
      bF[n] = *(const bf16x8*)&lB[(wc * 64 + n * 16 + fr) * 32 + kq * 8];
#pragma unroll
    for (int m = 0; m < 4; ++m)
#pragma unroll
      for (int n = 0; n < 4; ++n)
        acc[m][n] = __builtin_amdgcn_mfma_f32_16x16x32_bf16(aF[m], bF[n], acc[m][n], 0, 0, 0);
    __syncthreads();
  }

  CT* Cb = C + (size_t)blockIdx.z * sC;
#pragma unroll
  for (int m = 0; m < 4; ++m) {
    int rb = m0 + wr * 64 + m * 16 + kq * 4;
#pragma unroll
    for (int n = 0; n < 4; ++n) {
      int col = n0 + wc * 64 + n * 16 + fr;
#pragma unroll
      for (int r = 0; r < 4; ++r)
        storeC(&Cb[(size_t)(rb + r) * N + col], acc[m][n][r]);
    }
  }
}

// ---------------- K5: ew[b][o][i] = bf16(res + 0.9*sum_e g[b,e]*rtw[e]) ----------------
// grid 576 blocks, 256 threads, 4 floats per thread
__global__ __launch_bounds__(256) void k_combine(const float* __restrict__ rtw,
                                                 const float* __restrict__ res,
                                                 const float* __restrict__ g,
                                                 u16* __restrict__ ew) {
  __shared__ float gs[NB * NE];
  int tid = threadIdx.x;
  if (tid < NB * NE) gs[tid] = 0.9f * g[tid];
  __syncthreads();
  size_t base = ((size_t)blockIdx.x * 256 + tid) * 4;
  float4 rv[NE];
#pragma unroll
  for (int e = 0; e < NE; ++e)
    rv[e] = *(const float4*)(rtw + (size_t)e * (NOUT * NIN) + base);
  float4 r4 = *(const float4*)(res + base);
  for (int b = 0; b < NB; ++b) {
    float ax = r4.x, ay = r4.y, az = r4.z, aw = r4.w;
#pragma unroll
    for (int e = 0; e < NE; ++e) {
      float gg = gs[b * NE + e];
      ax += gg * rv[e].x; ay += gg * rv[e].y; az += gg * rv[e].z; aw += gg * rv[e].w;
    }
    ushort4 o;
    o.x = f2bf(ax); o.y = f2bf(ay); o.z = f2bf(az); o.w = f2bf(aw);
    *(ushort4*)(ew + (size_t)b * (NOUT * NIN) + base) = o;
  }
}

extern "C" void kernel_launch(void* const* d_in, const int* in_sizes, int n_in,
                              void* d_out, int out_size, void* d_ws, size_t ws_size,
                              hipStream_t stream) {
  const float* x = (const float*)d_in[0];
  const float* w_gate = (const float*)d_in[1];
  const float* weight = (const float*)d_in[2];
  const float* res_w = (const float*)d_in[3];
  const float* c1i = (const float*)d_in[4];
  const float* c2i = (const float*)d_in[5];
  const float* c1o = (const float*)d_in[6];
  const float* c2o = (const float*)d_in[7];

  char* ws = (char*)d_ws;
  float* part = (float*)(ws + OFF_PART);
  float* gates = (float*)(ws + OFF_GATES);
  u16* xbf = (u16*)(ws + OFF_XBF);
  u16* Min = (u16*)(ws + OFF_MIN);
  u16* Mout = (u16*)(ws + OFF_MOUT);
  u16* Wd = (u16*)(ws + OFF_WD);
  u16* T1t = (u16*)(ws + OFF_T1T);
  float* rtw = (float*)(ws + OFF_RTW);
  u16* ew = (u16*)(ws + OFF_EW);

  float* y = (float*)d_out;
  float* loss = y + YSZ;

  // 1) mean partials + x->bf16
  k_xm<<<dim3(256), 256, 0, stream>>>(x, part, xbf);
  // 2) gating + loss
  k_gate<<<dim3(1), 256, 0, stream>>>(part, w_gate, gates, loss);
  // 3) Kronecker factors + weight delta (bf16)
  k_prep<<<dim3(8, 48), 256, 0, stream>>>(weight, res_w, c1i, c2i, c1o, c2o, Min, Mout, Wd);
  // 4) pass A: T1t[i][jk] = sum_lm Min[i][lm] * Wd[jk][lm]
  gemm_bt<u16><<<dim3(6, 6, 8), 256, 0, stream>>>(
      Min, Wd, T1t, NIN, NOUT, NIN, (size_t)NIN * NIN, (size_t)NIN * NIN, (size_t)NIN * NIN);
  // 5) pass B: rtw[o][i] = sum_jk Mout[o][jk] * T1t[i][jk]
  gemm_bt<float><<<dim3(6, 6, 8), 256, 0, stream>>>(
      Mout, T1t, rtw, NOUT, NIN, NOUT, (size_t)NIN * NIN, (size_t)NIN * NIN, (size_t)NIN * NIN);
  // 6) combine into per-batch expert weights (bf16)
  k_combine<<<dim3(576), 256, 0, stream>>>(rtw, res_w, gates, ew);
  // 7) main grouped GEMM: y[b][s][o] = sum_i xbf[b][s][i] * ew[b][o][i]
  gemm_bt<float><<<dim3(4, 6, 16), 256, 0, stream>>>(
      xbf, ew, y, NS, NOUT, NIN, (size_t)NS * NIN, (size_t)NOUT * NIN, (size_t)NS * NIN);
}

// Round 2
// 132.417 us; speedup vs baseline: 1.1902x; 1.1902x over previous
//
#include <hip/hip_runtime.h>
#include <hip/hip_bf16.h>

typedef unsigned short u16;
typedef __attribute__((ext_vector_type(8))) short bf16x8;
typedef __attribute__((ext_vector_type(4))) float f32x4;

#define NE 8
#define NTOPK 4
#define NIN 768
#define NOUT 768
#define NB 16
#define NS 512
#define YSZ (NB * NS * NOUT)   // 6291456

// ---- workspace layout (bytes) ----
#define OFF_PART  0u           // 16*16*768 f32 partial sums  (786432 B used)
#define OFF_GATES 1048576u     // 16*8 f32
#define OFF_XBF   1049088u     // 16*512*768 bf16  = 12582912
#define OFF_MIN   13632000u    // 8*768*768 bf16   = 9437184
#define OFF_MOUT  23069184u    // 8*768*768 bf16
#define OFF_WD    32506368u    // 8*768*768 bf16
#define OFF_T1T   41943552u    // 8*768*768 bf16
#define OFF_RTW   51380736u    // 8*768*768 f32    = 18874368
#define OFF_EW    OFF_MIN      // 16*768*768 bf16 = 18874368, overlays Min+Mout (free after pass B)

__device__ __forceinline__ u16 f2bf(float f) {
  union { float f; unsigned u; } v; v.f = f;
  unsigned r = v.u + 0x7fffu + ((v.u >> 16) & 1u);
  return (u16)(r >> 16);
}

__device__ __forceinline__ void gload16(const void* g, void* l) {
  __builtin_amdgcn_global_load_lds(
      (const __attribute__((address_space(1))) unsigned int*)g,
      (__attribute__((address_space(3))) unsigned int*)l, 16, 0, 0);
}

__device__ __forceinline__ void storeC(float* p, float v) { *p = v; }
__device__ __forceinline__ void storeC(u16* p, float v) { *p = f2bf(v); }

// ---------------- K0: mean partials over S + x -> bf16 ----------------
// grid: 16 b * 16 sc = 256 blocks, 256 threads
__global__ __launch_bounds__(256) void k_xm(const float* __restrict__ x,
                                            float* __restrict__ part,
                                            u16* __restrict__ xbf) {
  int b = blockIdx.x >> 4;
  int sc = blockIdx.x & 15;
  int tid = threadIdx.x;
  float a0 = 0.f, a1 = 0.f, a2 = 0.f;
  int s0 = sc * 32;
  for (int s = s0; s < s0 + 32; ++s) {
    size_t ro = ((size_t)(b * NS + s)) * NIN;
    float v0 = x[ro + tid];
    float v1 = x[ro + tid + 256];
    float v2 = x[ro + tid + 512];
    a0 += v0; a1 += v1; a2 += v2;
    xbf[ro + tid]       = f2bf(v0);
    xbf[ro + tid + 256] = f2bf(v1);
    xbf[ro + tid + 512] = f2bf(v2);
  }
  size_t po = (size_t)(b * 16 + sc) * NIN;
  part[po + tid] = a0;
  part[po + tid + 256] = a1;
  part[po + tid + 512] = a2;
}

// ---------------- K1: logits + top-k softmax gates, 16 blocks (one per b) ----------------
__global__ __launch_bounds__(256) void k_logits(const float* __restrict__ part,
                                                const float* __restrict__ w_gate,
                                                float* __restrict__ gates_out) {
  int b = blockIdx.x;
  int tid = threadIdx.x;
  float p[NE] = {0.f, 0.f, 0.f, 0.f, 0.f, 0.f, 0.f, 0.f};
  for (int i = tid; i < NIN; i += 256) {
    float s = 0.f;
#pragma unroll
    for (int sc = 0; sc < 16; ++sc) s += part[(size_t)(b * 16 + sc) * NIN + i];
    float xmv = s * (1.0f / (float)NS);
#pragma unroll
    for (int e = 0; e < NE; ++e) p[e] += xmv * w_gate[i * NE + e];
  }
  __shared__ float red[4 * NE];
#pragma unroll
  for (int e = 0; e < NE; ++e) {
    float v = p[e];
    for (int off = 32; off; off >>= 1) v += __shfl_down(v, off);
    if ((tid & 63) == 0) red[(tid >> 6) * NE + e] = v;
  }
  __syncthreads();
  if (tid == 0) {
    float v[NE]; bool used[NE];
    for (int e = 0; e < NE; ++e) {
      v[e] = red[e] + red[NE + e] + red[2 * NE + e] + red[3 * NE + e];
      used[e] = false;
    }
    int idxs[NTOPK]; float vals[NTOPK];
    for (int t = 0; t < NTOPK; ++t) {
      int best = 0; float bv = -3.4e38f;
      for (int e = 0; e < NE; ++e)
        if (!used[e] && v[e] > bv) { bv = v[e]; best = e; }
      used[best] = true; idxs[t] = best; vals[t] = bv;
    }
    float m = vals[0];
    float ex[NTOPK]; float se = 0.f;
    for (int t = 0; t < NTOPK; ++t) { ex[t] = expf(vals[t] - m); se += ex[t]; }
    float g[NE];
    for (int e = 0; e < NE; ++e) g[e] = 0.f;
    for (int t = 0; t < NTOPK; ++t) g[idxs[t]] = ex[t] / se;
    for (int e = 0; e < NE; ++e) gates_out[b * NE + e] = g[e];
  }
}

// ---------------- K2: build Min, Mout (Kronecker), Wd = weight-res, all bf16 ----------------
// grid: (8, 48) blocks, 256 threads; each block does 16 rows
__global__ __launch_bounds__(256) void k_prep(const float* __restrict__ w,
                                              const float* __restrict__ res,
                                              const float* __restrict__ c1i,
                                              const float* __restrict__ c2i,
                                              const float* __restrict__ c1o,
                                              const float* __restrict__ c2o,
                                              u16* __restrict__ Min,
                                              u16* __restrict__ Mout,
                                              u16* __restrict__ Wd) {
  int e = blockIdx.x;
  int r0 = blockIdx.y * 16;
  int tid = threadIdx.x;
  for (int rr = 0; rr < 16; ++rr) {
    int r = r0 + rr;
    int r1 = r >> 5, r2 = r & 31;
    size_t rowo = ((size_t)e * NIN + r) * NIN;
    for (int c = tid; c < NIN; c += 256) {
      int l = c >> 5, mm = c & 31;
      float a = c1i[(e * 24 + r1) * 24 + l] * c2i[(e * 32 + r2) * 32 + mm];
      float b = c1o[(e * 24 + r1) * 24 + l] * c2o[(e * 32 + r2) * 32 + mm];
      Min[rowo + c] = f2bf(a);
      Mout[rowo + c] = f2bf(b);
      Wd[rowo + c] = f2bf(w[rowo + c] - res[(size_t)r * NIN + c]);
    }
  }
}

// ---------------- GEMM: C[m][n] = sum_k A[m][k]*B[n][k], bf16 in, CT out ----------------
// 128x128 tile, BK=32, 256 threads (4 waves 2x2), global_load_lds staging
template <typename CT>
__global__ __launch_bounds__(256) void gemm_bt(const u16* __restrict__ A,
                                               const u16* __restrict__ B,
                                               CT* __restrict__ C,
                                               int M, int N, int Kd,
                                               size_t sA, size_t sB, size_t sC) {
  __shared__ u16 lA[128 * 32];
  __shared__ u16 lB[128 * 32];
  const int tid = threadIdx.x;
  const int lane = tid & 63;
  const int w = tid >> 6;
  const int wr = w >> 1, wc = w & 1;
  const int fr = lane & 15;
  const int kq = lane >> 4;
  const int m0 = blockIdx.x * 128;
  const int n0 = blockIdx.y * 128;
  const u16* Ab = A + (size_t)blockIdx.z * sA;
  const u16* Bb = B + (size_t)blockIdx.z * sB;

  f32x4 acc[4][4] = {};

  for (int k0 = 0; k0 < Kd; k0 += 32) {
#pragma unroll
    for (int q = 0; q < 2; ++q) {
      int ob = (w * 2 + q) * 1024 + lane * 16;  // byte offset in 8KB tile
      int row = ob >> 6;                        // 64B per row (32 bf16)
      int colb = ob & 63;
      gload16((const char*)Ab + ((size_t)(m0 + row) * Kd + k0) * 2 + colb,
              (char*)lA + ob);
      gload16((const char*)Bb + ((size_t)(n0 + row) * Kd + k0) * 2 + colb,
              (char*)lB + ob);
    }
    __syncthreads();
    bf16x8 aF[4], bF[4];
#pragma unroll
    for (int m = 0; m < 4; ++m)
      aF[m] = *(const bf16x8*)&lA[(wr * 64 + m * 16 + fr) * 32 + kq * 8];
#pragma unroll
    for (int n = 0; n < 4; ++n)
      bF[n] = *(const bf16x8*)&lB[(wc * 64 + n * 16 + fr) * 32 + kq * 8];
#pragma unroll
    for (int m = 0; m < 4; ++m)
#pragma unroll
      for (int n = 0; n < 4; ++n)
        acc[m][n] = __builtin_amdgcn_mfma_f32_16x16x32_bf16(aF[m], bF[n], acc[m][n], 0, 0, 0);
    __syncthreads();
  }

  CT* Cb = C + (size_t)blockIdx.z * sC;
#pragma unroll
  for (int m = 0; m < 4; ++m) {
    int rb = m0 + wr * 64 + m * 16 + kq * 4;
#pragma unroll
    for (int n = 0; n < 4; ++n) {
      int col = n0 + wc * 64 + n * 16 + fr;
#pragma unroll
      for (int r = 0; r < 4; ++r)
        storeC(&Cb[(size_t)(rb + r) * N + col], acc[m][n][r]);
    }
  }
}

// ---------------- K5: ew[b][o][i] = bf16(res + 0.9*sum_e g[b,e]*rtw[e]) + loss ----------------
// grid 576 blocks, 256 threads, 4 floats per thread
__global__ __launch_bounds__(256) void k_combine(const float* __restrict__ rtw,
                                                 const float* __restrict__ res,
                                                 const float* __restrict__ g,
                                                 u16* __restrict__ ew,
                                                 float* __restrict__ loss_out) {
  __shared__ float gs[NB * NE];
  int tid = threadIdx.x;
  if (tid < NB * NE) gs[tid] = 0.9f * g[tid];
  __syncthreads();
  // loss (cv^2 of importance and load) on one lane of block 0
  if (blockIdx.x == 0 && tid == 0) {
    float imp[NE], ld[NE];
    for (int e = 0; e < NE; ++e) {
      float si = 0.f, sl = 0.f;
      for (int b = 0; b < NB; ++b) {
        float gg = g[b * NE + e];
        si += gg; sl += (gg > 0.f) ? 1.f : 0.f;
      }
      imp[e] = si; ld[e] = sl;
    }
    float loss = 0.f;
    for (int which = 0; which < 2; ++which) {
      const float* a = which ? ld : imp;
      float mean = 0.f;
      for (int e = 0; e < NE; ++e) mean += a[e];
      mean *= (1.0f / NE);
      float var = 0.f;
      for (int e = 0; e < NE; ++e) { float d = a[e] - mean; var += d * d; }
      var *= (1.0f / (NE - 1));
      loss += var / (mean * mean + 1e-10f);
    }
    loss_out[0] = 0.01f * loss;
  }
  size_t base = ((size_t)blockIdx.x * 256 + tid) * 4;
  float4 rv[NE];
#pragma unroll
  for (int e = 0; e < NE; ++e)
    rv[e] = *(const float4*)(rtw + (size_t)e * (NOUT * NIN) + base);
  float4 r4 = *(const float4*)(res + base);
  for (int b = 0; b < NB; ++b) {
    float ax = r4.x, ay = r4.y, az = r4.z, aw = r4.w;
#pragma unroll
    for (int e = 0; e < NE; ++e) {
      float gg = gs[b * NE + e];
      ax += gg * rv[e].x; ay += gg * rv[e].y; az += gg * rv[e].z; aw += gg * rv[e].w;
    }
    ushort4 o;
    o.x = f2bf(ax); o.y = f2bf(ay); o.z = f2bf(az); o.w = f2bf(aw);
    *(ushort4*)(ew + (size_t)b * (NOUT * NIN) + base) = o;
  }
}

extern "C" void kernel_launch(void* const* d_in, const int* in_sizes, int n_in,
                              void* d_out, int out_size, void* d_ws, size_t ws_size,
                              hipStream_t stream) {
  const float* x = (const float*)d_in[0];
  const float* w_gate = (const float*)d_in[1];
  const float* weight = (const float*)d_in[2];
  const float* res_w = (const float*)d_in[3];
  const float* c1i = (const float*)d_in[4];
  const float* c2i = (const float*)d_in[5];
  const float* c1o = (const float*)d_in[6];
  const float* c2o = (const float*)d_in[7];

  char* ws = (char*)d_ws;
  float* part = (float*)(ws + OFF_PART);
  float* gates = (float*)(ws + OFF_GATES);
  u16* xbf = (u16*)(ws + OFF_XBF);
  u16* Min = (u16*)(ws + OFF_MIN);
  u16* Mout = (u16*)(ws + OFF_MOUT);
  u16* Wd = (u16*)(ws + OFF_WD);
  u16* T1t = (u16*)(ws + OFF_T1T);
  float* rtw = (float*)(ws + OFF_RTW);
  u16* ew = (u16*)(ws + OFF_EW);

  float* y = (float*)d_out;
  float* loss = y + YSZ;

  // 1) mean partials + x->bf16
  k_xm<<<dim3(256), 256, 0, stream>>>(x, part, xbf);
  // 2) gating (16 blocks, one per batch row)
  k_logits<<<dim3(NB), 256, 0, stream>>>(part, w_gate, gates);
  // 3) Kronecker factors + weight delta (bf16)
  k_prep<<<dim3(8, 48), 256, 0, stream>>>(weight, res_w, c1i, c2i, c1o, c2o, Min, Mout, Wd);
  // 4) pass A: T1t[i][jk] = sum_lm Min[i][lm] * Wd[jk][lm]
  gemm_bt<u16><<<dim3(6, 6, 8), 256, 0, stream>>>(
      Min, Wd, T1t, NIN, NOUT, NIN, (size_t)NIN * NIN, (size_t)NIN * NIN, (size_t)NIN * NIN);
  // 5) pass B: rtw[o][i] = sum_jk Mout[o][jk] * T1t[i][jk]
  gemm_bt<float><<<dim3(6, 6, 8), 256, 0, stream>>>(
      Mout, T1t, rtw, NOUT, NIN, NOUT, (size_t)NIN * NIN, (size_t)NIN * NIN, (size_t)NIN * NIN);
  // 6) combine into per-batch expert weights (bf16) + loss
  k_combine<<<dim3(576), 256, 0, stream>>>(rtw, res_w, gates, ew, loss);
  // 7) main grouped GEMM: y[b][s][o] = sum_i xbf[b][s][i] * ew[b][o][i]
  gemm_bt<float><<<dim3(4, 6, 16), 256, 0, stream>>>(
      xbf, ew, y, NS, NOUT, NIN, (size_t)NS * NIN, (size_t)NOUT * NIN, (size_t)NS * NIN);
}

// Round 3
// 121.627 us; speedup vs baseline: 1.2957x; 1.0887x over previous
//
#include <hip/hip_runtime.h>
#include <hip/hip_bf16.h>

typedef unsigned short u16;
typedef __attribute__((ext_vector_type(8))) short bf16x8;
typedef __attribute__((ext_vector_type(4))) float f32x4;

#define NE 8
#define NTOPK 4
#define NIN 768
#define NOUT 768
#define NB 16
#define NS 512
#define YSZ (NB * NS * NOUT)   // 6291456
#define EWN (NOUT * NIN)       // 589824

// ---- workspace layout (bytes) ----
#define OFF_PART  0u           // 16*16*768 f32 partial sums  (786432 B used)
#define OFF_GATES 1048576u     // 16*8 f32
#define OFF_XBF   1049088u     // 16*512*768 bf16  = 12582912
#define OFF_MIN   13632000u    // 8*768*768 bf16   = 9437184
#define OFF_MOUT  23069184u    // 8*768*768 bf16
#define OFF_WD    32506368u    // 8*768*768 bf16
#define OFF_T1T   41943552u    // 8*768*768 bf16
#define OFF_RTW   51380736u    // 8*768*768 bf16 (9437184 B used)
#define OFF_EW    OFF_MIN      // 16*768*768 bf16 = 18874368, overlays Min+Mout (free after pass B)

__device__ __forceinline__ u16 f2bf(float f) {
  union { float f; unsigned u; } v; v.f = f;
  unsigned r = v.u + 0x7fffu + ((v.u >> 16) & 1u);
  return (u16)(r >> 16);
}
__device__ __forceinline__ float bf2f(u16 h) {
  union { unsigned u; float f; } v; v.u = ((unsigned)h) << 16;
  return v.f;
}

__device__ __forceinline__ void gload16(const void* g, void* l) {
  __builtin_amdgcn_global_load_lds(
      (const __attribute__((address_space(1))) unsigned int*)g,
      (__attribute__((address_space(3))) unsigned int*)l, 16, 0, 0);
}

__device__ __forceinline__ void storeC(float* p, float v) { *p = v; }
__device__ __forceinline__ void storeC(u16* p, float v) { *p = f2bf(v); }

// ---------------- K0: mean partials over S + x -> bf16 ----------------
// grid: 16 b * 16 sc = 256 blocks, 192 threads (thread t owns float4 column t)
__global__ __launch_bounds__(192) void k_xm(const float* __restrict__ x,
                                            float* __restrict__ part,
                                            u16* __restrict__ xbf) {
  int b = blockIdx.x >> 4;
  int sc = blockIdx.x & 15;
  int t = threadIdx.x;                      // 0..191
  int c = t * 4;
  float a0 = 0.f, a1 = 0.f, a2 = 0.f, a3 = 0.f;
  int s0 = sc * 32;
  for (int s = s0; s < s0 + 32; ++s) {
    size_t ro = ((size_t)(b * NS + s)) * NIN;
    float4 v = *(const float4*)(x + ro + c);
    a0 += v.x; a1 += v.y; a2 += v.z; a3 += v.w;
    ushort4 o;
    o.x = f2bf(v.x); o.y = f2bf(v.y); o.z = f2bf(v.z); o.w = f2bf(v.w);
    *(ushort4*)(xbf + ro + c) = o;
  }
  float4 pv; pv.x = a0; pv.y = a1; pv.z = a2; pv.w = a3;
  *(float4*)(part + (size_t)(b * 16 + sc) * NIN + c) = pv;
}

// ---------------- K1: logits + top-k softmax gates, 16 blocks (one per b) ----------------
__global__ __launch_bounds__(256) void k_logits(const float* __restrict__ part,
                                                const float* __restrict__ w_gate,
                                                float* __restrict__ gates_out) {
  int b = blockIdx.x;
  int tid = threadIdx.x;
  float p[NE] = {0.f, 0.f, 0.f, 0.f, 0.f, 0.f, 0.f, 0.f};
  for (int i = tid; i < NIN; i += 256) {
    float s = 0.f;
#pragma unroll
    for (int sc = 0; sc < 16; ++sc) s += part[(size_t)(b * 16 + sc) * NIN + i];
    float xmv = s * (1.0f / (float)NS);
#pragma unroll
    for (int e = 0; e < NE; ++e) p[e] += xmv * w_gate[i * NE + e];
  }
  __shared__ float red[4 * NE];
#pragma unroll
  for (int e = 0; e < NE; ++e) {
    float v = p[e];
    for (int off = 32; off; off >>= 1) v += __shfl_down(v, off);
    if ((tid & 63) == 0) red[(tid >> 6) * NE + e] = v;
  }
  __syncthreads();
  if (tid == 0) {
    float v[NE]; bool used[NE];
    for (int e = 0; e < NE; ++e) {
      v[e] = red[e] + red[NE + e] + red[2 * NE + e] + red[3 * NE + e];
      used[e] = false;
    }
    int idxs[NTOPK]; float vals[NTOPK];
    for (int t = 0; t < NTOPK; ++t) {
      int best = 0; float bv = -3.4e38f;
      for (int e = 0; e < NE; ++e)
        if (!used[e] && v[e] > bv) { bv = v[e]; best = e; }
      used[best] = true; idxs[t] = best; vals[t] = bv;
    }
    float m = vals[0];
    float ex[NTOPK]; float se = 0.f;
    for (int t = 0; t < NTOPK; ++t) { ex[t] = expf(vals[t] - m); se += ex[t]; }
    float g[NE];
    for (int e = 0; e < NE; ++e) g[e] = 0.f;
    for (int t = 0; t < NTOPK; ++t) g[idxs[t]] = ex[t] / se;
    for (int e = 0; e < NE; ++e) gates_out[b * NE + e] = g[e];
  }
}

// ---------------- K2: build Min, Mout (Kronecker), Wd = weight-res, all bf16 ----------------
// grid: (8, 48) blocks, 192 threads; each block does 16 rows, thread t owns cols 4t..4t+3
__global__ __launch_bounds__(192) void k_prep(const float* __restrict__ w,
                                              const float* __restrict__ res,
                                              const float* __restrict__ c1i,
                                              const float* __restrict__ c2i,
                                              const float* __restrict__ c1o,
                                              const float* __restrict__ c2o,
                                              u16* __restrict__ Min,
                                              u16* __restrict__ Mout,
                                              u16* __restrict__ Wd) {
  int e = blockIdx.x;
  int r0 = blockIdx.y * 16;
  int t = threadIdx.x;
  int c = t * 4;
  int l = c >> 5;           // same for all 4 cols (4 | 32)
  int mm = c & 31;
  for (int rr = 0; rr < 16; ++rr) {
    int r = r0 + rr;
    int r1 = r >> 5, r2 = r & 31;
    size_t rowo = ((size_t)e * NIN + r) * NIN;
    float ci1 = c1i[(e * 24 + r1) * 24 + l];
    float co1 = c1o[(e * 24 + r1) * 24 + l];
    float4 ci2 = *(const float4*)(c2i + (e * 32 + r2) * 32 + mm);
    float4 co2 = *(const float4*)(c2o + (e * 32 + r2) * 32 + mm);
    float4 wv = *(const float4*)(w + rowo + c);
    float4 rv = *(const float4*)(res + (size_t)r * NIN + c);
    ushort4 omin, omout, owd;
    omin.x = f2bf(ci1 * ci2.x); omin.y = f2bf(ci1 * ci2.y);
    omin.z = f2bf(ci1 * ci2.z); omin.w = f2bf(ci1 * ci2.w);
    omout.x = f2bf(co1 * co2.x); omout.y = f2bf(co1 * co2.y);
    omout.z = f2bf(co1 * co2.z); omout.w = f2bf(co1 * co2.w);
    owd.x = f2bf(wv.x - rv.x); owd.y = f2bf(wv.y - rv.y);
    owd.z = f2bf(wv.z - rv.z); owd.w = f2bf(wv.w - rv.w);
    *(ushort4*)(Min + rowo + c) = omin;
    *(ushort4*)(Mout + rowo + c) = omout;
    *(ushort4*)(Wd + rowo + c) = owd;
  }
}

// ---------------- GEMM: C[m][n] = sum_k A[m][k]*B[n][k], bf16 in, CT out ----------------
// 128x128 tile, BK=32, 256 threads (4 waves 2x2), double-buffered global_load_lds,
// one __syncthreads per K-step (2-phase minimum pipeline).
template <typename CT>
__global__ __launch_bounds__(256) void gemm_bt(const u16* __restrict__ A,
                                               const u16* __restrict__ B,
                                               CT* __restrict__ C,
                                               int M, int N, int Kd,
                                               size_t sA, size_t sB, size_t sC) {
  __shared__ u16 lA[2][128 * 32];
  __shared__ u16 lB[2][128 * 32];
  const int tid = threadIdx.x;
  const int lane = tid & 63;
  const int w = tid >> 6;
  const int wr = w >> 1, wc = w & 1;
  const int fr = lane & 15;
  const int kq = lane >> 4;
  const int m0 = blockIdx.x * 128;
  const int n0 = blockIdx.y * 128;
  const u16* Ab = A + (size_t)blockIdx.z * sA;
  const u16* Bb = B + (size_t)blockIdx.z * sB;

  const int ob = (w * 2) * 1024 + lane * 16;      // this thread's first byte slot
  const int ob2 = ob + 1024;                      // second slot (q=1)
  const int row1 = ob >> 6, colb1 = ob & 63;
  const int row2 = ob2 >> 6, colb2 = ob2 & 63;

  auto STAGE = [&](int k0, int s) {
    gload16((const char*)Ab + ((size_t)(m0 + row1) * Kd + k0) * 2 + colb1,
            (char*)&lA[s][0] + ob);
    gload16((const char*)Bb + ((size_t)(n0 + row1) * Kd + k0) * 2 + colb1,
            (char*)&lB[s][0] + ob);
    gload16((const char*)Ab + ((size_t)(m0 + row2) * Kd + k0) * 2 + colb2,
            (char*)&lA[s][0] + ob2);
    gload16((const char*)Bb + ((size_t)(n0 + row2) * Kd + k0) * 2 + colb2,
            (char*)&lB[s][0] + ob2);
  };

  f32x4 acc[4][4] = {};

  STAGE(0, 0);
  __syncthreads();

  int cur = 0;
  for (int k0 = 0; k0 < Kd; k0 += 32) {
    if (k0 + 32 < Kd) STAGE(k0 + 32, cur ^ 1);
    bf16x8 aF[4], bF[4];
#pragma unroll
    for (int m = 0; m < 4; ++m)
      aF[m] = *(const bf16x8*)&lA[cur][(wr * 64 + m * 16 + fr) * 32 + kq * 8];
#pragma unroll
    for (int n = 0; n < 4; ++n)
      bF[n] = *(const bf16x8*)&lB[cur][(wc * 64 + n * 16 + fr) * 32 + kq * 8];
#pragma unroll
    for (int m = 0; m < 4; ++m)
#pragma unroll
      for (int n = 0; n < 4; ++n)
        acc[m][n] = __builtin_amdgcn_mfma_f32_16x16x32_bf16(aF[m], bF[n], acc[m][n], 0, 0, 0);
    __syncthreads();   // drains vmcnt (next-tile stage) + ensures all reads of cur done
    cur ^= 1;
  }

  CT* Cb = C + (size_t)blockIdx.z * sC;
#pragma unroll
  for (int m = 0; m < 4; ++m) {
    int rb = m0 + wr * 64 + m * 16 + kq * 4;
#pragma unroll
    for (int n = 0; n < 4; ++n) {
      int col = n0 + wc * 64 + n * 16 + fr;
#pragma unroll
      for (int r = 0; r < 4; ++r)
        storeC(&Cb[(size_t)(rb + r) * N + col], acc[m][n][r]);
    }
  }
}

// ---------------- K5: ew[b][o][i] = bf16(res + 0.9*sum_e g[b,e]*rtw[e]) + loss ----------------
// rtw is bf16 now. grid 288 blocks, 256 threads, 8 elements per thread
__global__ __launch_bounds__(256) void k_combine(const u16* __restrict__ rtwb,
                                                 const float* __restrict__ res,
                                                 const float* __restrict__ g,
                                                 u16* __restrict__ ew,
                                                 float* __restrict__ loss_out) {
  __shared__ float gs[NB * NE];
  int tid = threadIdx.x;
  if (tid < NB * NE) gs[tid] = 0.9f * g[tid];
  __syncthreads();
  // loss (cv^2 of importance and load) on one lane of block 0
  if (blockIdx.x == 0 && tid == 0) {
    float imp[NE], ld[NE];
    for (int e = 0; e < NE; ++e) {
      float si = 0.f, sl = 0.f;
      for (int b = 0; b < NB; ++b) {
        float gg = g[b * NE + e];
        si += gg; sl += (gg > 0.f) ? 1.f : 0.f;
      }
      imp[e] = si; ld[e] = sl;
    }
    float loss = 0.f;
    for (int which = 0; which < 2; ++which) {
      const float* a = which ? ld : imp;
      float mean = 0.f;
      for (int e = 0; e < NE; ++e) mean += a[e];
      mean *= (1.0f / NE);
      float var = 0.f;
      for (int e = 0; e < NE; ++e) { float d = a[e] - mean; var += d * d; }
      var *= (1.0f / (NE - 1));
      loss += var / (mean * mean + 1e-10f);
    }
    loss_out[0] = 0.01f * loss;
  }
  size_t base = ((size_t)blockIdx.x * 256 + tid) * 8;
  float rv[NE][8];
#pragma unroll
  for (int e = 0; e < NE; ++e) {
    bf16x8 v = *(const bf16x8*)(rtwb + (size_t)e * EWN + base);
#pragma unroll
    for (int j = 0; j < 8; ++j) rv[e][j] = bf2f((u16)v[j]);
  }
  float r8[8];
  {
    float4 ra = *(const float4*)(res + base);
    float4 rb = *(const float4*)(res + base + 4);
    r8[0] = ra.x; r8[1] = ra.y; r8[2] = ra.z; r8[3] = ra.w;
    r8[4] = rb.x; r8[5] = rb.y; r8[6] = rb.z; r8[7] = rb.w;
  }
  for (int b = 0; b < NB; ++b) {
    float a[8];
#pragma unroll
    for (int j = 0; j < 8; ++j) a[j] = r8[j];
#pragma unroll
    for (int e = 0; e < NE; ++e) {
      float gg = gs[b * NE + e];
#pragma unroll
      for (int j = 0; j < 8; ++j) a[j] += gg * rv[e][j];
    }
    bf16x8 o;
#pragma unroll
    for (int j = 0; j < 8; ++j) o[j] = (short)f2bf(a[j]);
    *(bf16x8*)(ew + (size_t)b * EWN + base) = o;
  }
}

extern "C" void kernel_launch(void* const* d_in, const int* in_sizes, int n_in,
                              void* d_out, int out_size, void* d_ws, size_t ws_size,
                              hipStream_t stream) {
  const float* x = (const float*)d_in[0];
  const float* w_gate = (const float*)d_in[1];
  const float* weight = (const float*)d_in[2];
  const float* res_w = (const float*)d_in[3];
  const float* c1i = (const float*)d_in[4];
  const float* c2i = (const float*)d_in[5];
  const float* c1o = (const float*)d_in[6];
  const float* c2o = (const float*)d_in[7];

  char* ws = (char*)d_ws;
  float* part = (float*)(ws + OFF_PART);
  float* gates = (float*)(ws + OFF_GATES);
  u16* xbf = (u16*)(ws + OFF_XBF);
  u16* Min = (u16*)(ws + OFF_MIN);
  u16* Mout = (u16*)(ws + OFF_MOUT);
  u16* Wd = (u16*)(ws + OFF_WD);
  u16* T1t = (u16*)(ws + OFF_T1T);
  u16* rtwb = (u16*)(ws + OFF_RTW);
  u16* ew = (u16*)(ws + OFF_EW);

  float* y = (float*)d_out;
  float* loss = y + YSZ;

  // 1) mean partials + x->bf16
  k_xm<<<dim3(256), 192, 0, stream>>>(x, part, xbf);
  // 2) gating (16 blocks, one per batch row)
  k_logits<<<dim3(NB), 256, 0, stream>>>(part, w_gate, gates);
  // 3) Kronecker factors + weight delta (bf16)
  k_prep<<<dim3(8, 48), 192, 0, stream>>>(weight, res_w, c1i, c2i, c1o, c2o, Min, Mout, Wd);
  // 4) pass A: T1t[i][jk] = sum_lm Min[i][lm] * Wd[jk][lm]
  gemm_bt<u16><<<dim3(6, 6, 8), 256, 0, stream>>>(
      Min, Wd, T1t, NIN, NOUT, NIN, (size_t)NIN * NIN, (size_t)NIN * NIN, (size_t)NIN * NIN);
  // 5) pass B: rtw[o][i] = sum_jk Mout[o][jk] * T1t[i][jk]  (bf16 out)
  gemm_bt<u16><<<dim3(6, 6, 8), 256, 0, stream>>>(
      Mout, T1t, rtwb, NOUT, NIN, NOUT, (size_t)NIN * NIN, (size_t)NIN * NIN, (size_t)NIN * NIN);
  // 6) combine into per-batch expert weights (bf16) + loss
  k_combine<<<dim3(288), 256, 0, stream>>>(rtwb, res_w, gates, ew, loss);
  // 7) main grouped GEMM: y[b][s][o] = sum_i xbf[b][s][i] * ew[b][o][i]
  gemm_bt<float><<<dim3(4, 6, 16), 256, 0, stream>>>(
      xbf, ew, y, NS, NOUT, NIN, (size_t)NS * NIN, (size_t)NOUT * NIN, (size_t)NS * NIN);
}

// Round 4
// 89.209 us; speedup vs baseline: 1.7666x; 1.3634x over previous
//
#include <hip/hip_runtime.h>
#include <hip/hip_bf16.h>

typedef unsigned short u16;
typedef __attribute__((ext_vector_type(8))) short bf16x8;
typedef __attribute__((ext_vector_type(4))) float f32x4;

#define NE 8
#define NTOPK 4
#define NIN 768
#define NOUT 768
#define NB 16
#define NS 512
#define YSZ (NB * NS * NOUT)   // 6291456
#define EWN (NOUT * NIN)       // 589824

// ---- workspace layout (bytes) ----
#define OFF_PART  0u           // 16*16*768 f32
#define OFF_GATES 1048576u     // 16*8 f32
#define OFF_XBF   1049088u     // 16*512*768 bf16  = 12582912
#define OFF_WD    13632000u    // 8*768*768 bf16   = 9437184
#define OFF_T1T   23069184u    // 8*768*768 bf16
#define OFF_RTW   32506368u    // 8*768*768 bf16
#define OFF_EW    41943552u    // 16*768*768 bf16  = 18874368

__device__ __forceinline__ u16 f2bf(float f) {
  union { float f; unsigned u; } v; v.f = f;
  unsigned r = v.u + 0x7fffu + ((v.u >> 16) & 1u);
  return (u16)(r >> 16);
}
__device__ __forceinline__ float bf2f(u16 h) {
  union { unsigned u; float f; } v; v.u = ((unsigned)h) << 16;
  return v.f;
}
__device__ __forceinline__ unsigned cvt2(float a, float b) {
  unsigned r;
  asm("v_cvt_pk_bf16_f32 %0, %1, %2" : "=v"(r) : "v"(a), "v"(b));
  return r;
}

__device__ __forceinline__ void gload16(const void* g, void* l) {
  __builtin_amdgcn_global_load_lds(
      (const __attribute__((address_space(1))) unsigned int*)g,
      (__attribute__((address_space(3))) unsigned int*)l, 16, 0, 0);
}

__device__ __forceinline__ void storeC(float* p, float v) { *p = v; }
__device__ __forceinline__ void storeC(u16* p, float v) { *p = f2bf(v); }

// ---------------- K0: mean partials over S + x -> bf16 ----------------
__global__ __launch_bounds__(192) void k_xm(const float* __restrict__ x,
                                            float* __restrict__ part,
                                            u16* __restrict__ xbf) {
  int b = blockIdx.x >> 4;
  int sc = blockIdx.x & 15;
  int t = threadIdx.x;
  int c = t * 4;
  float a0 = 0.f, a1 = 0.f, a2 = 0.f, a3 = 0.f;
  int s0 = sc * 32;
  for (int s = s0; s < s0 + 32; ++s) {
    size_t ro = ((size_t)(b * NS + s)) * NIN;
    float4 v = *(const float4*)(x + ro + c);
    a0 += v.x; a1 += v.y; a2 += v.z; a3 += v.w;
    ushort4 o;
    o.x = f2bf(v.x); o.y = f2bf(v.y); o.z = f2bf(v.z); o.w = f2bf(v.w);
    *(ushort4*)(xbf + ro + c) = o;
  }
  float4 pv; pv.x = a0; pv.y = a1; pv.z = a2; pv.w = a3;
  *(float4*)(part + (size_t)(b * 16 + sc) * NIN + c) = pv;
}

// ---------------- K1: logits + top-k softmax gates ----------------
__global__ __launch_bounds__(256) void k_logits(const float* __restrict__ part,
                                                const float* __restrict__ w_gate,
                                                float* __restrict__ gates_out) {
  int b = blockIdx.x;
  int tid = threadIdx.x;
  float p[NE] = {0.f, 0.f, 0.f, 0.f, 0.f, 0.f, 0.f, 0.f};
  for (int i = tid; i < NIN; i += 256) {
    float s = 0.f;
#pragma unroll
    for (int sc = 0; sc < 16; ++sc) s += part[(size_t)(b * 16 + sc) * NIN + i];
    float xmv = s * (1.0f / (float)NS);
#pragma unroll
    for (int e = 0; e < NE; ++e) p[e] += xmv * w_gate[i * NE + e];
  }
  __shared__ float red[4 * NE];
#pragma unroll
  for (int e = 0; e < NE; ++e) {
    float v = p[e];
    for (int off = 32; off; off >>= 1) v += __shfl_down(v, off);
    if ((tid & 63) == 0) red[(tid >> 6) * NE + e] = v;
  }
  __syncthreads();
  if (tid == 0) {
    float v[NE]; bool used[NE];
    for (int e = 0; e < NE; ++e) {
      v[e] = red[e] + red[NE + e] + red[2 * NE + e] + red[3 * NE + e];
      used[e] = false;
    }
    int idxs[NTOPK]; float vals[NTOPK];
    for (int t = 0; t < NTOPK; ++t) {
      int best = 0; float bv = -3.4e38f;
      for (int e = 0; e < NE; ++e)
        if (!used[e] && v[e] > bv) { bv = v[e]; best = e; }
      used[best] = true; idxs[t] = best; vals[t] = bv;
    }
    float m = vals[0];
    float ex[NTOPK]; float se = 0.f;
    for (int t = 0; t < NTOPK; ++t) { ex[t] = expf(vals[t] - m); se += ex[t]; }
    float g[NE];
    for (int e = 0; e < NE; ++e) g[e] = 0.f;
    for (int t = 0; t < NTOPK; ++t) g[idxs[t]] = ex[t] / se;
    for (int e = 0; e < NE; ++e) gates_out[b * NE + e] = g[e];
  }
}

// ---------------- K2: Wd = bf16(weight - res) ----------------
// grid (288, 8), 256 threads, 8 elems/thread
__global__ __launch_bounds__(256) void k_wd(const float* __restrict__ w,
                                            const float* __restrict__ res,
                                            u16* __restrict__ Wd) {
  int e = blockIdx.y;
  size_t base = (size_t)blockIdx.x * 2048 + threadIdx.x * 8;
  float4 wa = *(const float4*)(w + (size_t)e * EWN + base);
  float4 wb = *(const float4*)(w + (size_t)e * EWN + base + 4);
  float4 ra = *(const float4*)(res + base);
  float4 rb = *(const float4*)(res + base + 4);
  bf16x8 o;
  o[0] = (short)f2bf(wa.x - ra.x); o[1] = (short)f2bf(wa.y - ra.y);
  o[2] = (short)f2bf(wa.z - ra.z); o[3] = (short)f2bf(wa.w - ra.w);
  o[4] = (short)f2bf(wb.x - rb.x); o[5] = (short)f2bf(wb.y - rb.y);
  o[6] = (short)f2bf(wb.z - rb.z); o[7] = (short)f2bf(wb.w - rb.w);
  *(bf16x8*)(Wd + (size_t)e * EWN + base) = o;
}

// ---------------- gemm_kron: C[e][m][n] = sum_k (c1[e]⊗c2[e])[m][k] * B[e][n][k] ----------------
// A computed in registers from Kronecker factors. BM=64, BN=128, BK=32, 4 waves (2x2).
// grid: 1D nwg = 12*6*8 = 576, XCD-chunk swizzled (chunk = 72 = one expert per XCD).
template <typename CT>
__global__ __launch_bounds__(256) void gemm_kron(const float* __restrict__ c1,  // [E][24][24]
                                                 const float* __restrict__ c2,  // [E][32][32]
                                                 const u16* __restrict__ B,    // [E][768][768]
                                                 CT* __restrict__ C) {         // [E][768][768]
  __shared__ u16 lB[2][128 * 32];
  const int tid = threadIdx.x;
  const int lane = tid & 63;
  const int w = tid >> 6;
  const int wr = w >> 1, wc = w & 1;
  const int fr = lane & 15;
  const int kq = lane >> 4;

  const int nwg = gridDim.x;
  const int swz = (blockIdx.x & 7) * (nwg >> 3) + (blockIdx.x >> 3);
  const int mb = swz % 12;
  const int nb = (swz / 12) % 6;
  const int e = swz / 72;

  const int m0 = mb * 64, n0 = nb * 128;
  const u16* Bb = B + (size_t)e * EWN;
  const float* c1b = c1 + e * 24 * 24;
  const float* c2b = c2 + e * 32 * 32;

  // wave rows: row = m0 + wr*32 + m*16 + fr (m=0,1) -> r1 = (m0>>5)+wr (same for both m),
  // r2 = m*16 + fr.
  const int r1a = (m0 >> 5) + wr;
  float c2r[2][8];
  {
    const float* p0 = c2b + fr * 32 + kq * 8;
    const float* p1 = c2b + (16 + fr) * 32 + kq * 8;
#pragma unroll
    for (int j = 0; j < 8; ++j) { c2r[0][j] = p0[j]; c2r[1][j] = p1[j]; }
  }

  const int ob1 = (w * 2) * 1024 + lane * 16;
  const int ob2 = ob1 + 1024;
  const int rowB1 = ob1 >> 6, colB1 = ob1 & 63;
  const int rowB2 = ob2 >> 6, colB2 = ob2 & 63;

  auto STAGE = [&](int k0, int s) {
    gload16((const char*)Bb + ((size_t)(n0 + rowB1) * NIN + k0) * 2 + colB1,
            (char*)&lB[s][0] + ob1);
    gload16((const char*)Bb + ((size_t)(n0 + rowB2) * NIN + k0) * 2 + colB2,
            (char*)&lB[s][0] + ob2);
  };

  f32x4 acc[2][4] = {};
  STAGE(0, 0);
  __syncthreads();
  int cur = 0;
  for (int k0 = 0; k0 < NIN; k0 += 32) {
    if (k0 + 32 < NIN) STAGE(k0 + 32, cur ^ 1);
    const int l0 = k0 >> 5;
    const float ca = c1b[r1a * 24 + l0];
    bf16x8 aF[2], bF[4];
#pragma unroll
    for (int m = 0; m < 2; ++m) {
      union { unsigned u[4]; bf16x8 v; } pk;
      pk.u[0] = cvt2(ca * c2r[m][0], ca * c2r[m][1]);
      pk.u[1] = cvt2(ca * c2r[m][2], ca * c2r[m][3]);
      pk.u[2] = cvt2(ca * c2r[m][4], ca * c2r[m][5]);
      pk.u[3] = cvt2(ca * c2r[m][6], ca * c2r[m][7]);
      aF[m] = pk.v;
    }
#pragma unroll
    for (int n = 0; n < 4; ++n)
      bF[n] = *(const bf16x8*)&lB[cur][(wc * 64 + n * 16 + fr) * 32 + kq * 8];
#pragma unroll
    for (int m = 0; m < 2; ++m)
#pragma unroll
      for (int n = 0; n < 4; ++n)
        acc[m][n] = __builtin_amdgcn_mfma_f32_16x16x32_bf16(aF[m], bF[n], acc[m][n], 0, 0, 0);
    __syncthreads();
    cur ^= 1;
  }

  CT* Cb = C + (size_t)e * EWN;
#pragma unroll
  for (int m = 0; m < 2; ++m) {
    int rb = m0 + wr * 32 + m * 16 + kq * 4;
#pragma unroll
    for (int n = 0; n < 4; ++n) {
      int col = n0 + wc * 64 + n * 16 + fr;
#pragma unroll
      for (int r = 0; r < 4; ++r)
        storeC(&Cb[(size_t)(rb + r) * NIN + col], acc[m][n][r]);
    }
  }
}

// ---------------- main GEMM: y[b][s][o] = sum_i A[b][s][i]*Bw[b][o][i] ----------------
// BM=64, BN=128, BK=32, 4 waves (2x2), double-buffered, XCD-chunk swizzled.
// grid: 1D nwg = 8*6*16 = 768 (chunk = 96 = two batch items per XCD).
__global__ __launch_bounds__(256) void gemm_main(const u16* __restrict__ A,
                                                 const u16* __restrict__ Bw,
                                                 float* __restrict__ C) {
  __shared__ u16 lA[2][64 * 32];
  __shared__ u16 lB[2][128 * 32];
  const int tid = threadIdx.x;
  const int lane = tid & 63;
  const int w = tid >> 6;
  const int wr = w >> 1, wc = w & 1;
  const int fr = lane & 15;
  const int kq = lane >> 4;

  const int nwg = gridDim.x;
  const int swz = (blockIdx.x & 7) * (nwg >> 3) + (blockIdx.x >> 3);
  const int mb = swz % 8;
  const int nb = (swz / 8) % 6;
  const int b = swz / 48;

  const int m0 = mb * 64, n0 = nb * 128;
  const u16* Ab = A + (size_t)b * NS * NIN;
  const u16* Bb = Bw + (size_t)b * EWN;

  const int obA = tid * 16;
  const int rowA = obA >> 6, colA = obA & 63;
  const int obB1 = (w * 2) * 1024 + lane * 16;
  const int obB2 = obB1 + 1024;
  const int rowB1 = obB1 >> 6, colB1 = obB1 & 63;
  const int rowB2 = obB2 >> 6, colB2 = obB2 & 63;

  auto STAGE = [&](int k0, int s) {
    gload16((const char*)Ab + ((size_t)(m0 + rowA) * NIN + k0) * 2 + colA,
            (char*)&lA[s][0] + obA);
    gload16((const char*)Bb + ((size_t)(n0 + rowB1) * NIN + k0) * 2 + colB1,
            (char*)&lB[s][0] + obB1);
    gload16((const char*)Bb + ((size_t)(n0 + rowB2) * NIN + k0) * 2 + colB2,
            (char*)&lB[s][0] + obB2);
  };

  f32x4 acc[2][4] = {};
  STAGE(0, 0);
  __syncthreads();
  int cur = 0;
  for (int k0 = 0; k0 < NIN; k0 += 32) {
    if (k0 + 32 < NIN) STAGE(k0 + 32, cur ^ 1);
    bf16x8 aF[2], bF[4];
#pragma unroll
    for (int m = 0; m < 2; ++m)
      aF[m] = *(const bf16x8*)&lA[cur][(wr * 32 + m * 16 + fr) * 32 + kq * 8];
#pragma unroll
    for (int n = 0; n < 4; ++n)
      bF[n] = *(const bf16x8*)&lB[cur][(wc * 64 + n * 16 + fr) * 32 + kq * 8];
#pragma unroll
    for (int m = 0; m < 2; ++m)
#pragma unroll
      for (int n = 0; n < 4; ++n)
        acc[m][n] = __builtin_amdgcn_mfma_f32_16x16x32_bf16(aF[m], bF[n], acc[m][n], 0, 0, 0);
    __syncthreads();
    cur ^= 1;
  }

  float* Cb = C + (size_t)b * NS * NOUT;
#pragma unroll
  for (int m = 0; m < 2; ++m) {
    int rb = m0 + wr * 32 + m * 16 + kq * 4;
#pragma unroll
    for (int n = 0; n < 4; ++n) {
      int col = n0 + wc * 64 + n * 16 + fr;
#pragma unroll
      for (int r = 0; r < 4; ++r)
        Cb[(size_t)(rb + r) * NOUT + col] = acc[m][n][r];
    }
  }
}

// ---------------- K5: ew = bf16(res + 0.9*sum_e g*rtw) + loss ----------------
__global__ __launch_bounds__(256) void k_combine(const u16* __restrict__ rtwb,
                                                 const float* __restrict__ res,
                                                 const float* __restrict__ g,
                                                 u16* __restrict__ ew,
                                                 float* __restrict__ loss_out) {
  __shared__ float gs[NB * NE];
  int tid = threadIdx.x;
  if (tid < NB * NE) gs[tid] = 0.9f * g[tid];
  __syncthreads();
  if (blockIdx.x == 0 && tid == 0) {
    float imp[NE], ld[NE];
    for (int e = 0; e < NE; ++e) {
      float si = 0.f, sl = 0.f;
      for (int b = 0; b < NB; ++b) {
        float gg = g[b * NE + e];
        si += gg; sl += (gg > 0.f) ? 1.f : 0.f;
      }
      imp[e] = si; ld[e] = sl;
    }
    float loss = 0.f;
    for (int which = 0; which < 2; ++which) {
      const float* a = which ? ld : imp;
      float mean = 0.f;
      for (int e = 0; e < NE; ++e) mean += a[e];
      mean *= (1.0f / NE);
      float var = 0.f;
      for (int e = 0; e < NE; ++e) { float d = a[e] - mean; var += d * d; }
      var *= (1.0f / (NE - 1));
      loss += var / (mean * mean + 1e-10f);
    }
    loss_out[0] = 0.01f * loss;
  }
  size_t base = ((size_t)blockIdx.x * 256 + tid) * 8;
  float rv[NE][8];
#pragma unroll
  for (int e = 0; e < NE; ++e) {
    bf16x8 v = *(const bf16x8*)(rtwb + (size_t)e * EWN + base);
#pragma unroll
    for (int j = 0; j < 8; ++j) rv[e][j] = bf2f((u16)v[j]);
  }
  float r8[8];
  {
    float4 ra = *(const float4*)(res + base);
    float4 rb = *(const float4*)(res + base + 4);
    r8[0] = ra.x; r8[1] = ra.y; r8[2] = ra.z; r8[3] = ra.w;
    r8[4] = rb.x; r8[5] = rb.y; r8[6] = rb.z; r8[7] = rb.w;
  }
  for (int b = 0; b < NB; ++b) {
    float a[8];
#pragma unroll
    for (int j = 0; j < 8; ++j) a[j] = r8[j];
#pragma unroll
    for (int e = 0; e < NE; ++e) {
      float gg = gs[b * NE + e];
#pragma unroll
      for (int j = 0; j < 8; ++j) a[j] += gg * rv[e][j];
    }
    bf16x8 o;
#pragma unroll
    for (int j = 0; j < 8; ++j) o[j] = (short)f2bf(a[j]);
    *(bf16x8*)(ew + (size_t)b * EWN + base) = o;
  }
}

extern "C" void kernel_launch(void* const* d_in, const int* in_sizes, int n_in,
                              void* d_out, int out_size, void* d_ws, size_t ws_size,
                              hipStream_t stream) {
  const float* x = (const float*)d_in[0];
  const float* w_gate = (const float*)d_in[1];
  const float* weight = (const float*)d_in[2];
  const float* res_w = (const float*)d_in[3];
  const float* c1i = (const float*)d_in[4];
  const float* c2i = (const float*)d_in[5];
  const float* c1o = (const float*)d_in[6];
  const float* c2o = (const float*)d_in[7];

  char* ws = (char*)d_ws;
  float* part = (float*)(ws + OFF_PART);
  float* gates = (float*)(ws + OFF_GATES);
  u16* xbf = (u16*)(ws + OFF_XBF);
  u16* Wd = (u16*)(ws + OFF_WD);
  u16* T1t = (u16*)(ws + OFF_T1T);
  u16* rtwb = (u16*)(ws + OFF_RTW);
  u16* ew = (u16*)(ws + OFF_EW);

  float* y = (float*)d_out;
  float* loss = y + YSZ;

  // 1) mean partials + x->bf16
  k_xm<<<dim3(256), 192, 0, stream>>>(x, part, xbf);
  // 2) gating
  k_logits<<<dim3(NB), 256, 0, stream>>>(part, w_gate, gates);
  // 3) Wd = bf16(weight - res)
  k_wd<<<dim3(288, 8), 256, 0, stream>>>(weight, res_w, Wd);
  // 4) pass A: T1t[e][i][jk] = sum_lm (c1i⊗c2i)[i][lm] * Wd[e][jk][lm]
  gemm_kron<u16><<<dim3(576), 256, 0, stream>>>(c1i, c2i, Wd, T1t);
  // 5) pass B: rtw[e][o][i] = sum_jk (c1o⊗c2o)[o][jk] * T1t[e][i][jk]
  gemm_kron<u16><<<dim3(576), 256, 0, stream>>>(c1o, c2o, T1t, rtwb);
  // 6) combine into per-batch expert weights (bf16) + loss
  k_combine<<<dim3(288), 256, 0, stream>>>(rtwb, res_w, gates, ew, loss);
  // 7) main grouped GEMM
  gemm_main<<<dim3(768), 256, 0, stream>>>(xbf, ew, y);
}

// Round 5
// 89.194 us; speedup vs baseline: 1.7669x; 1.0002x over previous
//
#include <hip/hip_runtime.h>
#include <hip/hip_bf16.h>

typedef unsigned short u16;
typedef __attribute__((ext_vector_type(8))) short bf16x8;
typedef __attribute__((ext_vector_type(4))) float f32x4;

#define NE 8
#define NTOPK 4
#define NIN 768
#define NOUT 768
#define NB 16
#define NS 512
#define YSZ (NB * NS * NOUT)   // 6291456
#define EWN (NOUT * NIN)       // 589824

// ---- workspace layout (bytes) ----
#define OFF_PART  0u           // 16*16*768 f32
#define OFF_GATES 1048576u     // 16*8 f32
#define OFF_XBF   1049088u     // 16*512*768 bf16  = 12582912
#define OFF_WD    13632000u    // 8*768*768 bf16   = 9437184
#define OFF_T1T   23069184u    // 8*768*768 bf16
#define OFF_RTW   32506368u    // 8*768*768 bf16
#define OFF_EW    41943552u    // 16*768*768 bf16  = 18874368

// pipeline barriers: counted vmcnt (T4), raw s_barrier, no vmcnt(0) in main loop
#define PRE_BAR(N) asm volatile("s_waitcnt vmcnt(" #N ")\n\ts_barrier" ::: "memory")
#define POST_BAR() asm volatile("s_waitcnt lgkmcnt(0)\n\ts_barrier" ::: "memory")

__device__ __forceinline__ u16 f2bf(float f) {
  union { float f; unsigned u; } v; v.f = f;
  unsigned r = v.u + 0x7fffu + ((v.u >> 16) & 1u);
  return (u16)(r >> 16);
}
__device__ __forceinline__ float bf2f(u16 h) {
  union { unsigned u; float f; } v; v.u = ((unsigned)h) << 16;
  return v.f;
}
__device__ __forceinline__ unsigned cvt2(float a, float b) {
  unsigned r;
  asm("v_cvt_pk_bf16_f32 %0, %1, %2" : "=v"(r) : "v"(a), "v"(b));
  return r;
}

__device__ __forceinline__ void gload16(const void* g, void* l) {
  __builtin_amdgcn_global_load_lds(
      (const __attribute__((address_space(1))) unsigned int*)g,
      (__attribute__((address_space(3))) unsigned int*)l, 16, 0, 0);
}

__device__ __forceinline__ void storeC(float* p, float v) { *p = v; }
__device__ __forceinline__ void storeC(u16* p, float v) { *p = f2bf(v); }

// ---------------- K0: (blocks 0..255) mean partials + x->bf16 ; (256..2559) Wd ----------------
__global__ __launch_bounds__(256) void k_xm_wd(const float* __restrict__ x,
                                               float* __restrict__ part,
                                               u16* __restrict__ xbf,
                                               const float* __restrict__ w,
                                               const float* __restrict__ res,
                                               u16* __restrict__ Wd) {
  int bid = blockIdx.x;
  if (bid < 256) {
    int t = threadIdx.x;
    if (t < 192) {
      int b = bid >> 4;
      int sc = bid & 15;
      int c = t * 4;
      float a0 = 0.f, a1 = 0.f, a2 = 0.f, a3 = 0.f;
      int s0 = sc * 32;
      for (int s = s0; s < s0 + 32; ++s) {
        size_t ro = ((size_t)(b * NS + s)) * NIN;
        float4 v = *(const float4*)(x + ro + c);
        a0 += v.x; a1 += v.y; a2 += v.z; a3 += v.w;
        ushort4 o;
        o.x = f2bf(v.x); o.y = f2bf(v.y); o.z = f2bf(v.z); o.w = f2bf(v.w);
        *(ushort4*)(xbf + ro + c) = o;
      }
      float4 pv; pv.x = a0; pv.y = a1; pv.z = a2; pv.w = a3;
      *(float4*)(part + (size_t)(b * 16 + sc) * NIN + c) = pv;
    }
  } else {
    int b2 = bid - 256;              // 0..2303
    int e = b2 / 288;
    int blk = b2 % 288;
    size_t base = (size_t)blk * 2048 + threadIdx.x * 8;
    float4 wa = *(const float4*)(w + (size_t)e * EWN + base);
    float4 wb = *(const float4*)(w + (size_t)e * EWN + base + 4);
    float4 ra = *(const float4*)(res + base);
    float4 rb = *(const float4*)(res + base + 4);
    bf16x8 o;
    o[0] = (short)f2bf(wa.x - ra.x); o[1] = (short)f2bf(wa.y - ra.y);
    o[2] = (short)f2bf(wa.z - ra.z); o[3] = (short)f2bf(wa.w - ra.w);
    o[4] = (short)f2bf(wb.x - rb.x); o[5] = (short)f2bf(wb.y - rb.y);
    o[6] = (short)f2bf(wb.z - rb.z); o[7] = (short)f2bf(wb.w - rb.w);
    *(bf16x8*)(Wd + (size_t)e * EWN + base) = o;
  }
}

// ---------------- K1: logits + top-k softmax gates ----------------
__global__ __launch_bounds__(256) void k_logits(const float* __restrict__ part,
                                                const float* __restrict__ w_gate,
                                                float* __restrict__ gates_out) {
  int b = blockIdx.x;
  int tid = threadIdx.x;
  float p[NE] = {0.f, 0.f, 0.f, 0.f, 0.f, 0.f, 0.f, 0.f};
  for (int i = tid; i < NIN; i += 256) {
    float s = 0.f;
#pragma unroll
    for (int sc = 0; sc < 16; ++sc) s += part[(size_t)(b * 16 + sc) * NIN + i];
    float xmv = s * (1.0f / (float)NS);
#pragma unroll
    for (int e = 0; e < NE; ++e) p[e] += xmv * w_gate[i * NE + e];
  }
  __shared__ float red[4 * NE];
#pragma unroll
  for (int e = 0; e < NE; ++e) {
    float v = p[e];
    for (int off = 32; off; off >>= 1) v += __shfl_down(v, off);
    if ((tid & 63) == 0) red[(tid >> 6) * NE + e] = v;
  }
  __syncthreads();
  if (tid == 0) {
    float v[NE]; bool used[NE];
    for (int e = 0; e < NE; ++e) {
      v[e] = red[e] + red[NE + e] + red[2 * NE + e] + red[3 * NE + e];
      used[e] = false;
    }
    int idxs[NTOPK]; float vals[NTOPK];
    for (int t = 0; t < NTOPK; ++t) {
      int best = 0; float bv = -3.4e38f;
      for (int e = 0; e < NE; ++e)
        if (!used[e] && v[e] > bv) { bv = v[e]; best = e; }
      used[best] = true; idxs[t] = best; vals[t] = bv;
    }
    float m = vals[0];
    float ex[NTOPK]; float se = 0.f;
    for (int t = 0; t < NTOPK; ++t) { ex[t] = expf(vals[t] - m); se += ex[t]; }
    float g[NE];
    for (int e = 0; e < NE; ++e) g[e] = 0.f;
    for (int t = 0; t < NTOPK; ++t) g[idxs[t]] = ex[t] / se;
    for (int e = 0; e < NE; ++e) gates_out[b * NE + e] = g[e];
  }
}

// ---------------- gemm_kron: C[e][m][n] = sum_k (c1[e]⊗c2[e])[m][k] * B[e][n][k] ----------------
// A built in registers. BM=64, BN=128, BK=32, depth-4 counted-vmcnt pipeline (L=2/step).
// grid: 576 blocks, XCD-chunked (72 = one expert per XCD). K-steps T = 24.
template <typename CT>
__global__ __launch_bounds__(256) void gemm_kron(const float* __restrict__ c1,  // [E][24][24]
                                                 const float* __restrict__ c2,  // [E][32][32]
                                                 const u16* __restrict__ B,    // [E][768][768]
                                                 CT* __restrict__ C) {         // [E][768][768]
  __shared__ u16 lB[4][128 * 32];
  const int tid = threadIdx.x;
  const int lane = tid & 63;
  const int w = tid >> 6;
  const int wr = w >> 1, wc = w & 1;
  const int fr = lane & 15;
  const int kq = lane >> 4;

  const int swz = (blockIdx.x & 7) * 72 + (blockIdx.x >> 3);
  const int mb = swz % 12;
  const int nb = (swz / 12) % 6;
  const int e = swz / 72;

  const int m0 = mb * 64, n0 = nb * 128;
  const u16* Bb = B + (size_t)e * EWN;
  const float* c1b = c1 + e * 24 * 24;
  const float* c2b = c2 + e * 32 * 32;

  const int r1a = (m0 >> 5) + wr;
  float c2r[2][8];
  {
    const float* p0 = c2b + fr * 32 + kq * 8;
    const float* p1 = c2b + (16 + fr) * 32 + kq * 8;
#pragma unroll
    for (int j = 0; j < 8; ++j) { c2r[0][j] = p0[j]; c2r[1][j] = p1[j]; }
  }

  const int ob1 = (w * 2) * 1024 + lane * 16;
  const int ob2 = ob1 + 1024;
  const int rowB1 = ob1 >> 6, colB1 = ob1 & 63;
  const int rowB2 = ob2 >> 6, colB2 = ob2 & 63;

  auto STAGE = [&](int t, int s) {
    int k0 = t * 32;
    gload16((const char*)Bb + ((size_t)(n0 + rowB1) * NIN + k0) * 2 + colB1,
            (char*)&lB[s][0] + ob1);
    gload16((const char*)Bb + ((size_t)(n0 + rowB2) * NIN + k0) * 2 + colB2,
            (char*)&lB[s][0] + ob2);
  };

  f32x4 acc[2][4] = {};

  auto COMPUTE = [&](int t, int s) {
    const float ca = c1b[r1a * 24 + t];   // l0 = k0>>5 = t
    bf16x8 aF[2], bF[4];
#pragma unroll
    for (int m = 0; m < 2; ++m) {
      union { unsigned u[4]; bf16x8 v; } pk;
      pk.u[0] = cvt2(ca * c2r[m][0], ca * c2r[m][1]);
      pk.u[1] = cvt2(ca * c2r[m][2], ca * c2r[m][3]);
      pk.u[2] = cvt2(ca * c2r[m][4], ca * c2r[m][5]);
      pk.u[3] = cvt2(ca * c2r[m][6], ca * c2r[m][7]);
      aF[m] = pk.v;
    }
#pragma unroll
    for (int n = 0; n < 4; ++n)
      bF[n] = *(const bf16x8*)&lB[s][(wc * 64 + n * 16 + fr) * 32 + kq * 8];
#pragma unroll
    for (int m = 0; m < 2; ++m)
#pragma unroll
      for (int n = 0; n < 4; ++n)
        acc[m][n] = __builtin_amdgcn_mfma_f32_16x16x32_bf16(aF[m], bF[n], acc[m][n], 0, 0, 0);
  };

  STAGE(0, 0); STAGE(1, 1); STAGE(2, 2);
  for (int t = 0; t < 21; ++t) {
    STAGE(t + 3, (t + 3) & 3);
    PRE_BAR(6);
    COMPUTE(t, t & 3);
    POST_BAR();
  }
  PRE_BAR(4);  COMPUTE(21, 1);  POST_BAR();
  PRE_BAR(2);  COMPUTE(22, 2);  POST_BAR();
  PRE_BAR(0);  COMPUTE(23, 3);

  CT* Cb = C + (size_t)e * EWN;
#pragma unroll
  for (int m = 0; m < 2; ++m) {
    int rb = m0 + wr * 32 + m * 16 + kq * 4;
#pragma unroll
    for (int n = 0; n < 4; ++n) {
      int col = n0 + wc * 64 + n * 16 + fr;
#pragma unroll
      for (int r = 0; r < 4; ++r)
        storeC(&Cb[(size_t)(rb + r) * NIN + col], acc[m][n][r]);
    }
  }
}

// ---------------- main GEMM: y[b][s][o] = sum_i A[b][s][i]*Bw[b][o][i] ----------------
// BM=64, BN=128, BK=32, depth-4 counted-vmcnt pipeline (L=3/step).
// grid: 768 blocks, XCD-chunked (96 = two batch items per XCD). T = 24.
__global__ __launch_bounds__(256) void gemm_main(const u16* __restrict__ A,
                                                 const u16* __restrict__ Bw,
                                                 float* __restrict__ C) {
  __shared__ u16 lA[4][64 * 32];
  __shared__ u16 lB[4][128 * 32];
  const int tid = threadIdx.x;
  const int lane = tid & 63;
  const int w = tid >> 6;
  const int wr = w >> 1, wc = w & 1;
  const int fr = lane & 15;
  const int kq = lane >> 4;

  const int swz = (blockIdx.x & 7) * 96 + (blockIdx.x >> 3);
  const int mb = swz % 8;
  const int nb = (swz / 8) % 6;
  const int b = swz / 48;

  const int m0 = mb * 64, n0 = nb * 128;
  const u16* Ab = A + (size_t)b * NS * NIN;
  const u16* Bb = Bw + (size_t)b * EWN;

  const int obA = tid * 16;
  const int rowA = obA >> 6, colA = obA & 63;
  const int obB1 = (w * 2) * 1024 + lane * 16;
  const int obB2 = obB1 + 1024;
  const int rowB1 = obB1 >> 6, colB1 = obB1 & 63;
  const int rowB2 = obB2 >> 6, colB2 = obB2 & 63;

  auto STAGE = [&](int t, int s) {
    int k0 = t * 32;
    gload16((const char*)Ab + ((size_t)(m0 + rowA) * NIN + k0) * 2 + colA,
            (char*)&lA[s][0] + obA);
    gload16((const char*)Bb + ((size_t)(n0 + rowB1) * NIN + k0) * 2 + colB1,
            (char*)&lB[s][0] + obB1);
    gload16((const char*)Bb + ((size_t)(n0 + rowB2) * NIN + k0) * 2 + colB2,
            (char*)&lB[s][0] + obB2);
  };

  f32x4 acc[2][4] = {};

  auto COMPUTE = [&](int s) {
    bf16x8 aF[2], bF[4];
#pragma unroll
    for (int m = 0; m < 2; ++m)
      aF[m] = *(const bf16x8*)&lA[s][(wr * 32 + m * 16 + fr) * 32 + kq * 8];
#pragma unroll
    for (int n = 0; n < 4; ++n)
      bF[n] = *(const bf16x8*)&lB[s][(wc * 64 + n * 16 + fr) * 32 + kq * 8];
#pragma unroll
    for (int m = 0; m < 2; ++m)
#pragma unroll
      for (int n = 0; n < 4; ++n)
        acc[m][n] = __builtin_amdgcn_mfma_f32_16x16x32_bf16(aF[m], bF[n], acc[m][n], 0, 0, 0);
  };

  STAGE(0, 0); STAGE(1, 1); STAGE(2, 2);
  for (int t = 0; t < 21; ++t) {
    STAGE(t + 3, (t + 3) & 3);
    PRE_BAR(9);
    COMPUTE(t & 3);
    POST_BAR();
  }
  PRE_BAR(6);  COMPUTE(1);  POST_BAR();
  PRE_BAR(3);  COMPUTE(2);  POST_BAR();
  PRE_BAR(0);  COMPUTE(3);

  float* Cb = C + (size_t)b * NS * NOUT;
#pragma unroll
  for (int m = 0; m < 2; ++m) {
    int rb = m0 + wr * 32 + m * 16 + kq * 4;
#pragma unroll
    for (int n = 0; n < 4; ++n) {
      int col = n0 + wc * 64 + n * 16 + fr;
#pragma unroll
      for (int r = 0; r < 4; ++r)
        Cb[(size_t)(rb + r) * NOUT + col] = acc[m][n][r];
    }
  }
}

// ---------------- K5: ew = bf16(res + 0.9*sum_e g*rtw) + loss ----------------
__global__ __launch_bounds__(256) void k_combine(const u16* __restrict__ rtwb,
                                                 const float* __restrict__ res,
                                                 const float* __restrict__ g,
                                                 u16* __restrict__ ew,
                                                 float* __restrict__ loss_out) {
  __shared__ float gs[NB * NE];
  int tid = threadIdx.x;
  if (tid < NB * NE) gs[tid] = 0.9f * g[tid];
  __syncthreads();
  if (blockIdx.x == 0 && tid == 0) {
    float imp[NE], ld[NE];
    for (int e = 0; e < NE; ++e) {
      float si = 0.f, sl = 0.f;
      for (int b = 0; b < NB; ++b) {
        float gg = g[b * NE + e];
        si += gg; sl += (gg > 0.f) ? 1.f : 0.f;
      }
      imp[e] = si; ld[e] = sl;
    }
    float loss = 0.f;
    for (int which = 0; which < 2; ++which) {
      const float* a = which ? ld : imp;
      float mean = 0.f;
      for (int e = 0; e < NE; ++e) mean += a[e];
      mean *= (1.0f / NE);
      float var = 0.f;
      for (int e = 0; e < NE; ++e) { float d = a[e] - mean; var += d * d; }
      var *= (1.0f / (NE - 1));
      loss += var / (mean * mean + 1e-10f);
    }
    loss_out[0] = 0.01f * loss;
  }
  size_t base = ((size_t)blockIdx.x * 256 + tid) * 8;
  float rv[NE][8];
#pragma unroll
  for (int e = 0; e < NE; ++e) {
    bf16x8 v = *(const bf16x8*)(rtwb + (size_t)e * EWN + base);
#pragma unroll
    for (int j = 0; j < 8; ++j) rv[e][j] = bf2f((u16)v[j]);
  }
  float r8[8];
  {
    float4 ra = *(const float4*)(res + base);
    float4 rb = *(const float4*)(res + base + 4);
    r8[0] = ra.x; r8[1] = ra.y; r8[2] = ra.z; r8[3] = ra.w;
    r8[4] = rb.x; r8[5] = rb.y; r8[6] = rb.z; r8[7] = rb.w;
  }
  for (int b = 0; b < NB; ++b) {
    float a[8];
#pragma unroll
    for (int j = 0; j < 8; ++j) a[j] = r8[j];
#pragma unroll
    for (int e = 0; e < NE; ++e) {
      float gg = gs[b * NE + e];
#pragma unroll
      for (int j = 0; j < 8; ++j) a[j] += gg * rv[e][j];
    }
    bf16x8 o;
#pragma unroll
    for (int j = 0; j < 8; ++j) o[j] = (short)f2bf(a[j]);
    *(bf16x8*)(ew + (size_t)b * EWN + base) = o;
  }
}

extern "C" void kernel_launch(void* const* d_in, const int* in_sizes, int n_in,
                              void* d_out, int out_size, void* d_ws, size_t ws_size,
                              hipStream_t stream) {
  const float* x = (const float*)d_in[0];
  const float* w_gate = (const float*)d_in[1];
  const float* weight = (const float*)d_in[2];
  const float* res_w = (const float*)d_in[3];
  const float* c1i = (const float*)d_in[4];
  const float* c2i = (const float*)d_in[5];
  const float* c1o = (const float*)d_in[6];
  const float* c2o = (const float*)d_in[7];

  char* ws = (char*)d_ws;
  float* part = (float*)(ws + OFF_PART);
  float* gates = (float*)(ws + OFF_GATES);
  u16* xbf = (u16*)(ws + OFF_XBF);
  u16* Wd = (u16*)(ws + OFF_WD);
  u16* T1t = (u16*)(ws + OFF_T1T);
  u16* rtwb = (u16*)(ws + OFF_RTW);
  u16* ew = (u16*)(ws + OFF_EW);

  float* y = (float*)d_out;
  float* loss = y + YSZ;

  // 1) mean partials + x->bf16 (blocks 0..255) and Wd (blocks 256..2559)
  k_xm_wd<<<dim3(2560), 256, 0, stream>>>(x, part, xbf, weight, res_w, Wd);
  // 2) gating
  k_logits<<<dim3(NB), 256, 0, stream>>>(part, w_gate, gates);
  // 3) pass A: T1t[e][i][jk] = sum_lm (c1i⊗c2i)[i][lm] * Wd[e][jk][lm]
  gemm_kron<u16><<<dim3(576), 256, 0, stream>>>(c1i, c2i, Wd, T1t);
  // 4) pass B: rtw[e][o][i] = sum_jk (c1o⊗c2o)[o][jk] * T1t[e][i][jk]
  gemm_kron<u16><<<dim3(576), 256, 0, stream>>>(c1o, c2o, T1t, rtwb);
  // 5) combine into per-batch expert weights (bf16) + loss
  k_combine<<<dim3(288), 256, 0, stream>>>(rtwb, res_w, gates, ew, loss);
  // 6) main grouped GEMM
  gemm_main<<<dim3(768), 256, 0, stream>>>(xbf, ew, y);
}

// Round 6
// 83.998 us; speedup vs baseline: 1.8762x; 1.0619x over previous
//
#include <hip/hip_runtime.h>
#include <hip/hip_bf16.h>

typedef unsigned short u16;
typedef __attribute__((ext_vector_type(8))) short bf16x8;
typedef __attribute__((ext_vector_type(4))) float f32x4;

#define NE 8
#define NTOPK 4
#define NIN 768
#define NOUT 768
#define NB 16
#define NS 512
#define YSZ (NB * NS * NOUT)   // 6291456
#define EWN (NOUT * NIN)       // 589824

// ---- workspace layout (bytes), total 62,915,072 ----
#define OFF_PART  0u           // 16*64*768 f32 = 3145728
#define OFF_GATES 3145728u     // 16*8 f32
#define OFF_XBF   3146240u     // 16*512*768 bf16 = 12582912
#define OFF_WD    15729152u    // 8*768*768 bf16  = 9437184
#define OFF_T1T   25166336u    // 8*768*768 bf16
#define OFF_RTW   34603520u    // 8*768*768 bf16
#define OFF_EW    44040704u    // 16*768*768 bf16 = 18874368

// pipeline barriers: counted vmcnt (T4), raw s_barrier, no vmcnt(0) in main loop
#define PRE_BAR(N) asm volatile("s_waitcnt vmcnt(" #N ")\n\ts_barrier" ::: "memory")
#define POST_BAR() asm volatile("s_waitcnt lgkmcnt(0)\n\ts_barrier" ::: "memory")

__device__ __forceinline__ u16 f2bf(float f) {
  union { float f; unsigned u; } v; v.f = f;
  unsigned r = v.u + 0x7fffu + ((v.u >> 16) & 1u);
  return (u16)(r >> 16);
}
__device__ __forceinline__ float bf2f(u16 h) {
  union { unsigned u; float f; } v; v.u = ((unsigned)h) << 16;
  return v.f;
}
__device__ __forceinline__ unsigned cvt2(float a, float b) {
  unsigned r;
  asm("v_cvt_pk_bf16_f32 %0, %1, %2" : "=v"(r) : "v"(a), "v"(b));
  return r;
}

__device__ __forceinline__ void gload16(const void* g, void* l) {
  __builtin_amdgcn_global_load_lds(
      (const __attribute__((address_space(1))) unsigned int*)g,
      (__attribute__((address_space(3))) unsigned int*)l, 16, 0, 0);
}

__device__ __forceinline__ void storeC(float* p, float v) { *p = v; }
__device__ __forceinline__ void storeC(u16* p, float v) { *p = f2bf(v); }

// ---------------- K0: (blocks 0..1023) mean partials + x->bf16 ; (1024..3327) Wd ----------------
__global__ __launch_bounds__(256) void k_xm_wd(const float* __restrict__ x,
                                               float* __restrict__ part,
                                               u16* __restrict__ xbf,
                                               const float* __restrict__ w,
                                               const float* __restrict__ res,
                                               u16* __restrict__ Wd) {
  int bid = blockIdx.x;
  if (bid < 1024) {
    int t = threadIdx.x;
    if (t < 192) {
      int b = bid >> 6;
      int sc = bid & 63;
      int c = t * 4;
      float a0 = 0.f, a1 = 0.f, a2 = 0.f, a3 = 0.f;
      int s0 = sc * 8;
#pragma unroll
      for (int r = 0; r < 8; ++r) {
        size_t ro = ((size_t)(b * NS + s0 + r)) * NIN;
        float4 v = *(const float4*)(x + ro + c);
        a0 += v.x; a1 += v.y; a2 += v.z; a3 += v.w;
        ushort4 o;
        o.x = f2bf(v.x); o.y = f2bf(v.y); o.z = f2bf(v.z); o.w = f2bf(v.w);
        *(ushort4*)(xbf + ro + c) = o;
      }
      float4 pv; pv.x = a0; pv.y = a1; pv.z = a2; pv.w = a3;
      *(float4*)(part + (size_t)(b * 64 + sc) * NIN + c) = pv;
    }
  } else {
    int b2 = bid - 1024;              // 0..2303
    int e = b2 / 288;
    int blk = b2 % 288;
    size_t base = (size_t)blk * 2048 + threadIdx.x * 8;
    float4 wa = *(const float4*)(w + (size_t)e * EWN + base);
    float4 wb = *(const float4*)(w + (size_t)e * EWN + base + 4);
    float4 ra = *(const float4*)(res + base);
    float4 rb = *(const float4*)(res + base + 4);
    bf16x8 o;
    o[0] = (short)f2bf(wa.x - ra.x); o[1] = (short)f2bf(wa.y - ra.y);
    o[2] = (short)f2bf(wa.z - ra.z); o[3] = (short)f2bf(wa.w - ra.w);
    o[4] = (short)f2bf(wb.x - rb.x); o[5] = (short)f2bf(wb.y - rb.y);
    o[6] = (short)f2bf(wb.z - rb.z); o[7] = (short)f2bf(wb.w - rb.w);
    *(bf16x8*)(Wd + (size_t)e * EWN + base) = o;
  }
}

// ---------------- gemm_kron: C[e][m][n] = sum_k (c1[e]⊗c2[e])[m][k] * B[e][n][k] ----------------
// A built in registers. BM=64, BN=128, BK=32, depth-4 counted-vmcnt pipeline.
// grid: 576 kron blocks (XCD-chunked, 72 = one expert per XCD) + optional 16 logits blocks.
__global__ __launch_bounds__(256) void gemm_kron(const float* __restrict__ c1,  // [E][24][24]
                                                 const float* __restrict__ c2,  // [E][32][32]
                                                 const u16* __restrict__ B,    // [E][768][768]
                                                 u16* __restrict__ C,          // [E][768][768]
                                                 const float* __restrict__ part,
                                                 const float* __restrict__ w_gate,
                                                 float* __restrict__ gates_out) {
  __shared__ u16 lB[4][128 * 32];
  __shared__ float red[4 * NE];
  const int tid = threadIdx.x;

  if (blockIdx.x >= 576) {
    // ---- folded k_logits: one block per batch row ----
    if (!gates_out) return;
    int b = blockIdx.x - 576;
    float p[NE] = {0.f, 0.f, 0.f, 0.f, 0.f, 0.f, 0.f, 0.f};
    for (int i = tid; i < NIN; i += 256) {
      float s = 0.f;
#pragma unroll
      for (int sc = 0; sc < 64; ++sc) s += part[(size_t)(b * 64 + sc) * NIN + i];
      float xmv = s * (1.0f / (float)NS);
#pragma unroll
      for (int e = 0; e < NE; ++e) p[e] += xmv * w_gate[i * NE + e];
    }
#pragma unroll
    for (int e = 0; e < NE; ++e) {
      float v = p[e];
      for (int off = 32; off; off >>= 1) v += __shfl_down(v, off);
      if ((tid & 63) == 0) red[(tid >> 6) * NE + e] = v;
    }
    __syncthreads();
    if (tid == 0) {
      float v[NE]; bool used[NE];
      for (int e = 0; e < NE; ++e) {
        v[e] = red[e] + red[NE + e] + red[2 * NE + e] + red[3 * NE + e];
        used[e] = false;
      }
      int idxs[NTOPK]; float vals[NTOPK];
      for (int t = 0; t < NTOPK; ++t) {
        int best = 0; float bv = -3.4e38f;
        for (int e = 0; e < NE; ++e)
          if (!used[e] && v[e] > bv) { bv = v[e]; best = e; }
        used[best] = true; idxs[t] = best; vals[t] = bv;
      }
      float m = vals[0];
      float ex[NTOPK]; float se = 0.f;
      for (int t = 0; t < NTOPK; ++t) { ex[t] = expf(vals[t] - m); se += ex[t]; }
      float g[NE];
      for (int e = 0; e < NE; ++e) g[e] = 0.f;
      for (int t = 0; t < NTOPK; ++t) g[idxs[t]] = ex[t] / se;
      for (int e = 0; e < NE; ++e) gates_out[b * NE + e] = g[e];
    }
    return;
  }

  const int lane = tid & 63;
  const int w = tid >> 6;
  const int wr = w >> 1, wc = w & 1;
  const int fr = lane & 15;
  const int kq = lane >> 4;

  const int swz = (blockIdx.x & 7) * 72 + (blockIdx.x >> 3);
  const int mb = swz % 12;
  const int nb = (swz / 12) % 6;
  const int e = swz / 72;

  const int m0 = mb * 64, n0 = nb * 128;
  const u16* Bb = B + (size_t)e * EWN;
  const float* c1b = c1 + e * 24 * 24;
  const float* c2b = c2 + e * 32 * 32;

  const int r1a = (m0 >> 5) + wr;
  float c2r[2][8];
  {
    const float* p0 = c2b + fr * 32 + kq * 8;
    const float* p1 = c2b + (16 + fr) * 32 + kq * 8;
#pragma unroll
    for (int j = 0; j < 8; ++j) { c2r[0][j] = p0[j]; c2r[1][j] = p1[j]; }
  }

  const int ob1 = (w * 2) * 1024 + lane * 16;
  const int ob2 = ob1 + 1024;
  const int rowB1 = ob1 >> 6, colB1 = ob1 & 63;
  const int rowB2 = ob2 >> 6, colB2 = ob2 & 63;

  auto STAGE = [&](int t, int s) {
    int k0 = t * 32;
    gload16((const char*)Bb + ((size_t)(n0 + rowB1) * NIN + k0) * 2 + colB1,
            (char*)&lB[s][0] + ob1);
    gload16((const char*)Bb + ((size_t)(n0 + rowB2) * NIN + k0) * 2 + colB2,
            (char*)&lB[s][0] + ob2);
  };

  f32x4 acc[2][4] = {};

  auto COMPUTE = [&](int t, int s) {
    const float ca = c1b[r1a * 24 + t];   // l0 = k0>>5 = t
    bf16x8 aF[2], bF[4];
#pragma unroll
    for (int m = 0; m < 2; ++m) {
      union { unsigned u[4]; bf16x8 v; } pk;
      pk.u[0] = cvt2(ca * c2r[m][0], ca * c2r[m][1]);
      pk.u[1] = cvt2(ca * c2r[m][2], ca * c2r[m][3]);
      pk.u[2] = cvt2(ca * c2r[m][4], ca * c2r[m][5]);
      pk.u[3] = cvt2(ca * c2r[m][6], ca * c2r[m][7]);
      aF[m] = pk.v;
    }
#pragma unroll
    for (int n = 0; n < 4; ++n)
      bF[n] = *(const bf16x8*)&lB[s][(wc * 64 + n * 16 + fr) * 32 + kq * 8];
#pragma unroll
    for (int m = 0; m < 2; ++m)
#pragma unroll
      for (int n = 0; n < 4; ++n)
        acc[m][n] = __builtin_amdgcn_mfma_f32_16x16x32_bf16(aF[m], bF[n], acc[m][n], 0, 0, 0);
  };

  STAGE(0, 0); STAGE(1, 1); STAGE(2, 2);
  for (int t = 0; t < 21; ++t) {
    STAGE(t + 3, (t + 3) & 3);
    PRE_BAR(6);
    COMPUTE(t, t & 3);
    POST_BAR();
  }
  PRE_BAR(4);  COMPUTE(21, 1);  POST_BAR();
  PRE_BAR(2);  COMPUTE(22, 2);  POST_BAR();
  PRE_BAR(0);  COMPUTE(23, 3);

  u16* Cb = C + (size_t)e * EWN;
#pragma unroll
  for (int m = 0; m < 2; ++m) {
    int rb = m0 + wr * 32 + m * 16 + kq * 4;
#pragma unroll
    for (int n = 0; n < 4; ++n) {
      int col = n0 + wc * 64 + n * 16 + fr;
#pragma unroll
      for (int r = 0; r < 4; ++r)
        storeC(&Cb[(size_t)(rb + r) * NIN + col], acc[m][n][r]);
    }
  }
}

// ---------------- main GEMM: y[b][s][o] = sum_i A[b][s][i]*Bw[b][o][i] ----------------
// BM=64, BN=128, BK=32, depth-4 counted-vmcnt pipeline (L=3/step).
// grid: 768 blocks, XCD-chunked (96 = two batch items per XCD). T = 24.
__global__ __launch_bounds__(256) void gemm_main(const u16* __restrict__ A,
                                                 const u16* __restrict__ Bw,
                                                 float* __restrict__ C) {
  __shared__ u16 lA[4][64 * 32];
  __shared__ u16 lB[4][128 * 32];
  const int tid = threadIdx.x;
  const int lane = tid & 63;
  const int w = tid >> 6;
  const int wr = w >> 1, wc = w & 1;
  const int fr = lane & 15;
  const int kq = lane >> 4;

  const int swz = (blockIdx.x & 7) * 96 + (blockIdx.x >> 3);
  const int mb = swz % 8;
  const int nb = (swz / 8) % 6;
  const int b = swz / 48;

  const int m0 = mb * 64, n0 = nb * 128;
  const u16* Ab = A + (size_t)b * NS * NIN;
  const u16* Bb = Bw + (size_t)b * EWN;

  const int obA = tid * 16;
  const int rowA = obA >> 6, colA = obA & 63;
  const int obB1 = (w * 2) * 1024 + lane * 16;
  const int obB2 = obB1 + 1024;
  const int rowB1 = obB1 >> 6, colB1 = obB1 & 63;
  const int rowB2 = obB2 >> 6, colB2 = obB2 & 63;

  auto STAGE = [&](int t, int s) {
    int k0 = t * 32;
    gload16((const char*)Ab + ((size_t)(m0 + rowA) * NIN + k0) * 2 + colA,
            (char*)&lA[s][0] + obA);
    gload16((const char*)Bb + ((size_t)(n0 + rowB1) * NIN + k0) * 2 + colB1,
            (char*)&lB[s][0] + obB1);
    gload16((const char*)Bb + ((size_t)(n0 + rowB2) * NIN + k0) * 2 + colB2,
            (char*)&lB[s][0] + obB2);
  };

  f32x4 acc[2][4] = {};

  auto COMPUTE = [&](int s) {
    bf16x8 aF[2], bF[4];
#pragma unroll
    for (int m = 0; m < 2; ++m)
      aF[m] = *(const bf16x8*)&lA[s][(wr * 32 + m * 16 + fr) * 32 + kq * 8];
#pragma unroll
    for (int n = 0; n < 4; ++n)
      bF[n] = *(const bf16x8*)&lB[s][(wc * 64 + n * 16 + fr) * 32 + kq * 8];
#pragma unroll
    for (int m = 0; m < 2; ++m)
#pragma unroll
      for (int n = 0; n < 4; ++n)
        acc[m][n] = __builtin_amdgcn_mfma_f32_16x16x32_bf16(aF[m], bF[n], acc[m][n], 0, 0, 0);
  };

  STAGE(0, 0); STAGE(1, 1); STAGE(2, 2);
  for (int t = 0; t < 21; ++t) {
    STAGE(t + 3, (t + 3) & 3);
    PRE_BAR(9);
    COMPUTE(t & 3);
    POST_BAR();
  }
  PRE_BAR(6);  COMPUTE(1);  POST_BAR();
  PRE_BAR(3);  COMPUTE(2);  POST_BAR();
  PRE_BAR(0);  COMPUTE(3);

  float* Cb = C + (size_t)b * NS * NOUT;
#pragma unroll
  for (int m = 0; m < 2; ++m) {
    int rb = m0 + wr * 32 + m * 16 + kq * 4;
#pragma unroll
    for (int n = 0; n < 4; ++n) {
      int col = n0 + wc * 64 + n * 16 + fr;
#pragma unroll
      for (int r = 0; r < 4; ++r)
        Cb[(size_t)(rb + r) * NOUT + col] = acc[m][n][r];
    }
  }
}

// ---------------- K5: ew = bf16(res + 0.9*sum_e g*rtw) + loss ----------------
__global__ __launch_bounds__(256) void k_combine(const u16* __restrict__ rtwb,
                                                 const float* __restrict__ res,
                                                 const float* __restrict__ g,
                                                 u16* __restrict__ ew,
                                                 float* __restrict__ loss_out) {
  __shared__ float gs[NB * NE];
  int tid = threadIdx.x;
  if (tid < NB * NE) gs[tid] = 0.9f * g[tid];
  __syncthreads();
  if (blockIdx.x == 0 && tid == 0) {
    float imp[NE], ld[NE];
    for (int e = 0; e < NE; ++e) {
      float si = 0.f, sl = 0.f;
      for (int b = 0; b < NB; ++b) {
        float gg = g[b * NE + e];
        si += gg; sl += (gg > 0.f) ? 1.f : 0.f;
      }
      imp[e] = si; ld[e] = sl;
    }
    float loss = 0.f;
    for (int which = 0; which < 2; ++which) {
      const float* a = which ? ld : imp;
      float mean = 0.f;
      for (int e = 0; e < NE; ++e) mean += a[e];
      mean *= (1.0f / NE);
      float var = 0.f;
      for (int e = 0; e < NE; ++e) { float d = a[e] - mean; var += d * d; }
      var *= (1.0f / (NE - 1));
      loss += var / (mean * mean + 1e-10f);
    }
    loss_out[0] = 0.01f * loss;
  }
  size_t base = ((size_t)blockIdx.x * 256 + tid) * 8;
  float rv[NE][8];
#pragma unroll
  for (int e = 0; e < NE; ++e) {
    bf16x8 v = *(const bf16x8*)(rtwb + (size_t)e * EWN + base);
#pragma unroll
    for (int j = 0; j < 8; ++j) rv[e][j] = bf2f((u16)v[j]);
  }
  float r8[8];
  {
    float4 ra = *(const float4*)(res + base);
    float4 rb = *(const float4*)(res + base + 4);
    r8[0] = ra.x; r8[1] = ra.y; r8[2] = ra.z; r8[3] = ra.w;
    r8[4] = rb.x; r8[5] = rb.y; r8[6] = rb.z; r8[7] = rb.w;
  }
  for (int b = 0; b < NB; ++b) {
    float a[8];
#pragma unroll
    for (int j = 0; j < 8; ++j) a[j] = r8[j];
#pragma unroll
    for (int e = 0; e < NE; ++e) {
      float gg = gs[b * NE + e];
#pragma unroll
      for (int j = 0; j < 8; ++j) a[j] += gg * rv[e][j];
    }
    bf16x8 o;
#pragma unroll
    for (int j = 0; j < 8; ++j) o[j] = (short)f2bf(a[j]);
    *(bf16x8*)(ew + (size_t)b * EWN + base) = o;
  }
}

extern "C" void kernel_launch(void* const* d_in, const int* in_sizes, int n_in,
                              void* d_out, int out_size, void* d_ws, size_t ws_size,
                              hipStream_t stream) {
  const float* x = (const float*)d_in[0];
  const float* w_gate = (const float*)d_in[1];
  const float* weight = (const float*)d_in[2];
  const float* res_w = (const float*)d_in[3];
  const float* c1i = (const float*)d_in[4];
  const float* c2i = (const float*)d_in[5];
  const float* c1o = (const float*)d_in[6];
  const float* c2o = (const float*)d_in[7];

  char* ws = (char*)d_ws;
  float* part = (float*)(ws + OFF_PART);
  float* gates = (float*)(ws + OFF_GATES);
  u16* xbf = (u16*)(ws + OFF_XBF);
  u16* Wd = (u16*)(ws + OFF_WD);
  u16* T1t = (u16*)(ws + OFF_T1T);
  u16* rtwb = (u16*)(ws + OFF_RTW);
  u16* ew = (u16*)(ws + OFF_EW);

  float* y = (float*)d_out;
  float* loss = y + YSZ;

  // 1) mean partials + x->bf16 (blocks 0..1023) and Wd (blocks 1024..3327)
  k_xm_wd<<<dim3(3328), 256, 0, stream>>>(x, part, xbf, weight, res_w, Wd);
  // 2) pass A: T1t[e][i][jk] = sum_lm (c1i⊗c2i)[i][lm] * Wd[e][jk][lm]
  //    + folded gating (blocks 576..591)
  gemm_kron<<<dim3(592), 256, 0, stream>>>(c1i, c2i, Wd, T1t, part, w_gate, gates);
  // 3) pass B: rtw[e][o][i] = sum_jk (c1o⊗c2o)[o][jk] * T1t[e][i][jk]
  gemm_kron<<<dim3(576), 256, 0, stream>>>(c1o, c2o, T1t, rtwb, nullptr, nullptr, nullptr);
  // 4) combine into per-batch expert weights (bf16) + loss
  k_combine<<<dim3(288), 256, 0, stream>>>(rtwb, res_w, gates, ew, loss);
  // 5) main grouped GEMM
  gemm_main<<<dim3(768), 256, 0, stream>>>(xbf, ew, y);
}

// Round 7
// 76.943 us; speedup vs baseline: 2.0482x; 1.0917x over previous
//
#include <hip/hip_runtime.h>
#include <hip/hip_bf16.h>

typedef unsigned short u16;
typedef __attribute__((ext_vector_type(8))) short bf16x8;
typedef __attribute__((ext_vector_type(4))) float f32x4;

#define NE 8
#define NTOPK 4
#define NIN 768
#define NOUT 768
#define NB 16
#define NS 512
#define YSZ (NB * NS * NOUT)   // 6291456
#define EWN (NOUT * NIN)       // 589824

// ---- workspace layout (bytes), total 62,915,072 ----
#define OFF_PART  0u           // 16*64*768 f32 = 3145728
#define OFF_GATES 3145728u     // 16*8 f32
#define OFF_XBF   3146240u     // 16*512*768 bf16 = 12582912
#define OFF_WD    15729152u    // 8*768*768 bf16  = 9437184
#define OFF_T1T   25166336u    // 8*768*768 bf16
#define OFF_RTW   34603520u    // 8*768*768 bf16
#define OFF_EW    44040704u    // 16*768*768 bf16 = 18874368

// pipeline barriers: counted vmcnt (T4), raw s_barrier, no vmcnt(0) in main loop
#define PRE_BAR(N) asm volatile("s_waitcnt vmcnt(" #N ")\n\ts_barrier" ::: "memory")
#define POST_BAR() asm volatile("s_waitcnt lgkmcnt(0)\n\ts_barrier" ::: "memory")

__device__ __forceinline__ u16 f2bf(float f) {
  union { float f; unsigned u; } v; v.f = f;
  unsigned r = v.u + 0x7fffu + ((v.u >> 16) & 1u);
  return (u16)(r >> 16);
}
__device__ __forceinline__ float bf2f(u16 h) {
  union { unsigned u; float f; } v; v.u = ((unsigned)h) << 16;
  return v.f;
}
__device__ __forceinline__ unsigned cvt2(float a, float b) {
  unsigned r;
  asm("v_cvt_pk_bf16_f32 %0, %1, %2" : "=v"(r) : "v"(a), "v"(b));
  return r;
}

__device__ __forceinline__ void gload16(const void* g, void* l) {
  __builtin_amdgcn_global_load_lds(
      (const __attribute__((address_space(1))) unsigned int*)g,
      (__attribute__((address_space(3))) unsigned int*)l, 16, 0, 0);
}

__device__ __forceinline__ void storeC(float* p, float v) { *p = v; }
__device__ __forceinline__ void storeC(u16* p, float v) { *p = f2bf(v); }

// ---------------- K0: (blocks 0..1023) mean partials + x->bf16 ; (1024..3327) Wd ----------------
__global__ __launch_bounds__(256) void k_xm_wd(const float* __restrict__ x,
                                               float* __restrict__ part,
                                               u16* __restrict__ xbf,
                                               const float* __restrict__ w,
                                               const float* __restrict__ res,
                                               u16* __restrict__ Wd) {
  int bid = blockIdx.x;
  if (bid < 1024) {
    int t = threadIdx.x;
    if (t < 192) {
      int b = bid >> 6;
      int sc = bid & 63;
      int c = t * 4;
      float a0 = 0.f, a1 = 0.f, a2 = 0.f, a3 = 0.f;
      int s0 = sc * 8;
#pragma unroll
      for (int r = 0; r < 8; ++r) {
        size_t ro = ((size_t)(b * NS + s0 + r)) * NIN;
        float4 v = *(const float4*)(x + ro + c);
        a0 += v.x; a1 += v.y; a2 += v.z; a3 += v.w;
        ushort4 o;
        o.x = f2bf(v.x); o.y = f2bf(v.y); o.z = f2bf(v.z); o.w = f2bf(v.w);
        *(ushort4*)(xbf + ro + c) = o;
      }
      float4 pv; pv.x = a0; pv.y = a1; pv.z = a2; pv.w = a3;
      *(float4*)(part + (size_t)(b * 64 + sc) * NIN + c) = pv;
    }
  } else {
    int b2 = bid - 1024;              // 0..2303
    int e = b2 / 288;
    int blk = b2 % 288;
    size_t base = (size_t)blk * 2048 + threadIdx.x * 8;
    float4 wa = *(const float4*)(w + (size_t)e * EWN + base);
    float4 wb = *(const float4*)(w + (size_t)e * EWN + base + 4);
    float4 ra = *(const float4*)(res + base);
    float4 rb = *(const float4*)(res + base + 4);
    bf16x8 o;
    o[0] = (short)f2bf(wa.x - ra.x); o[1] = (short)f2bf(wa.y - ra.y);
    o[2] = (short)f2bf(wa.z - ra.z); o[3] = (short)f2bf(wa.w - ra.w);
    o[4] = (short)f2bf(wb.x - rb.x); o[5] = (short)f2bf(wb.y - rb.y);
    o[6] = (short)f2bf(wb.z - rb.z); o[7] = (short)f2bf(wb.w - rb.w);
    *(bf16x8*)(Wd + (size_t)e * EWN + base) = o;
  }
}

// ---------------- gemm_kron: C[e][m][n] = sum_k (c1[e]⊗c2[e])[m][k] * B[e][n][k] ----------------
// A built in registers. BM=64, BN=128, BK=32, 4-buffer ring, 2 K-tiles per barrier region.
// grid: 576 kron blocks (XCD-chunked, 72 = one expert per XCD) + optional 16 logits blocks.
__global__ __launch_bounds__(256) void gemm_kron(const float* __restrict__ c1,  // [E][24][24]
                                                 const float* __restrict__ c2,  // [E][32][32]
                                                 const u16* __restrict__ B,    // [E][768][768]
                                                 u16* __restrict__ C,          // [E][768][768]
                                                 const float* __restrict__ part,
                                                 const float* __restrict__ w_gate,
                                                 float* __restrict__ gates_out) {
  __shared__ u16 lB[4][128 * 32];
  __shared__ float red[4 * NE];
  const int tid = threadIdx.x;

  if (blockIdx.x >= 576) {
    // ---- folded k_logits: one block per batch row ----
    if (!gates_out) return;
    int b = blockIdx.x - 576;
    float p[NE] = {0.f, 0.f, 0.f, 0.f, 0.f, 0.f, 0.f, 0.f};
    for (int i = tid; i < NIN; i += 256) {
      float s = 0.f;
#pragma unroll
      for (int sc = 0; sc < 64; ++sc) s += part[(size_t)(b * 64 + sc) * NIN + i];
      float xmv = s * (1.0f / (float)NS);
#pragma unroll
      for (int e = 0; e < NE; ++e) p[e] += xmv * w_gate[i * NE + e];
    }
#pragma unroll
    for (int e = 0; e < NE; ++e) {
      float v = p[e];
      for (int off = 32; off; off >>= 1) v += __shfl_down(v, off);
      if ((tid & 63) == 0) red[(tid >> 6) * NE + e] = v;
    }
    __syncthreads();
    if (tid == 0) {
      float v[NE]; bool used[NE];
      for (int e = 0; e < NE; ++e) {
        v[e] = red[e] + red[NE + e] + red[2 * NE + e] + red[3 * NE + e];
        used[e] = false;
      }
      int idxs[NTOPK]; float vals[NTOPK];
      for (int t = 0; t < NTOPK; ++t) {
        int best = 0; float bv = -3.4e38f;
        for (int e = 0; e < NE; ++e)
          if (!used[e] && v[e] > bv) { bv = v[e]; best = e; }
        used[best] = true; idxs[t] = best; vals[t] = bv;
      }
      float m = vals[0];
      float ex[NTOPK]; float se = 0.f;
      for (int t = 0; t < NTOPK; ++t) { ex[t] = expf(vals[t] - m); se += ex[t]; }
      float g[NE];
      for (int e = 0; e < NE; ++e) g[e] = 0.f;
      for (int t = 0; t < NTOPK; ++t) g[idxs[t]] = ex[t] / se;
      for (int e = 0; e < NE; ++e) gates_out[b * NE + e] = g[e];
    }
    return;
  }

  const int lane = tid & 63;
  const int w = tid >> 6;
  const int wr = w >> 1, wc = w & 1;
  const int fr = lane & 15;
  const int kq = lane >> 4;

  const int swz = (blockIdx.x & 7) * 72 + (blockIdx.x >> 3);
  const int mb = swz % 12;
  const int nb = (swz / 12) % 6;
  const int e = swz / 72;

  const int m0 = mb * 64, n0 = nb * 128;
  const u16* Bb = B + (size_t)e * EWN;
  const float* c1b = c1 + e * 24 * 24;
  const float* c2b = c2 + e * 32 * 32;

  const int r1a = (m0 >> 5) + wr;
  float c2r[2][8];
  {
    const float* p0 = c2b + fr * 32 + kq * 8;
    const float* p1 = c2b + (16 + fr) * 32 + kq * 8;
#pragma unroll
    for (int j = 0; j < 8; ++j) { c2r[0][j] = p0[j]; c2r[1][j] = p1[j]; }
  }

  const int ob1 = (w * 2) * 1024 + lane * 16;
  const int ob2 = ob1 + 1024;
  const int rowB1 = ob1 >> 6, colB1 = ob1 & 63;
  const int rowB2 = ob2 >> 6, colB2 = ob2 & 63;

  auto STAGE = [&](int t) {
    int s = t & 3;
    int k0 = t * 32;
    gload16((const char*)Bb + ((size_t)(n0 + rowB1) * NIN + k0) * 2 + colB1,
            (char*)&lB[s][0] + ob1);
    gload16((const char*)Bb + ((size_t)(n0 + rowB2) * NIN + k0) * 2 + colB2,
            (char*)&lB[s][0] + ob2);
  };

  f32x4 acc[2][4] = {};

  auto COMPUTE = [&](int t) {
    int s = t & 3;
    const float ca = c1b[r1a * 24 + t];   // l0 = k0>>5 = t (wave-uniform)
    bf16x8 aF[2], bF[4];
#pragma unroll
    for (int m = 0; m < 2; ++m) {
      union { unsigned u[4]; bf16x8 v; } pk;
      pk.u[0] = cvt2(ca * c2r[m][0], ca * c2r[m][1]);
      pk.u[1] = cvt2(ca * c2r[m][2], ca * c2r[m][3]);
      pk.u[2] = cvt2(ca * c2r[m][4], ca * c2r[m][5]);
      pk.u[3] = cvt2(ca * c2r[m][6], ca * c2r[m][7]);
      aF[m] = pk.v;
    }
#pragma unroll
    for (int n = 0; n < 4; ++n)
      bF[n] = *(const bf16x8*)&lB[s][(wc * 64 + n * 16 + fr) * 32 + kq * 8];
#pragma unroll
    for (int m = 0; m < 2; ++m)
#pragma unroll
      for (int n = 0; n < 4; ++n)
        acc[m][n] = __builtin_amdgcn_mfma_f32_16x16x32_bf16(aF[m], bF[n], acc[m][n], 0, 0, 0);
  };

  // prologue: 4 tiles in flight (8 loads)
  STAGE(0); STAGE(1); STAGE(2); STAGE(3);
  // 10 paired iterations: compute tiles 2i,2i+1; then stage 2i+4,2i+5
  for (int i = 0; i < 10; ++i) {
    PRE_BAR(4);                   // tiles 2i,2i+1 landed (2 tiles = 4 loads in flight)
    COMPUTE(2 * i); COMPUTE(2 * i + 1);
    POST_BAR();                   // all reads of bufs (2i&3),(2i+1&3) retired
    STAGE(2 * i + 4); STAGE(2 * i + 5);
  }
  PRE_BAR(4);  COMPUTE(20); COMPUTE(21);  POST_BAR();
  PRE_BAR(0);  COMPUTE(22); COMPUTE(23);

  u16* Cb = C + (size_t)e * EWN;
#pragma unroll
  for (int m = 0; m < 2; ++m) {
    int rb = m0 + wr * 32 + m * 16 + kq * 4;
#pragma unroll
    for (int n = 0; n < 4; ++n) {
      int col = n0 + wc * 64 + n * 16 + fr;
#pragma unroll
      for (int r = 0; r < 4; ++r)
        storeC(&Cb[(size_t)(rb + r) * NIN + col], acc[m][n][r]);
    }
  }
}

// ---------------- main GEMM: y[b][s][o] = sum_i A[b][s][i]*Bw[b][o][i] ----------------
// BM=64, BN=128, BK=32, 4-buffer ring, 2 K-tiles per barrier region (3 loads/thread/tile).
// grid: 768 blocks, XCD-chunked (96 = two batch items per XCD). T = 24.
__global__ __launch_bounds__(256) void gemm_main(const u16* __restrict__ A,
                                                 const u16* __restrict__ Bw,
                                                 float* __restrict__ C) {
  __shared__ u16 lA[4][64 * 32];
  __shared__ u16 lB[4][128 * 32];
  const int tid = threadIdx.x;
  const int lane = tid & 63;
  const int w = tid >> 6;
  const int wr = w >> 1, wc = w & 1;
  const int fr = lane & 15;
  const int kq = lane >> 4;

  const int swz = (blockIdx.x & 7) * 96 + (blockIdx.x >> 3);
  const int mb = swz % 8;
  const int nb = (swz / 8) % 6;
  const int b = swz / 48;

  const int m0 = mb * 64, n0 = nb * 128;
  const u16* Ab = A + (size_t)b * NS * NIN;
  const u16* Bb = Bw + (size_t)b * EWN;

  const int obA = tid * 16;
  const int rowA = obA >> 6, colA = obA & 63;
  const int obB1 = (w * 2) * 1024 + lane * 16;
  const int obB2 = obB1 + 1024;
  const int rowB1 = obB1 >> 6, colB1 = obB1 & 63;
  const int rowB2 = obB2 >> 6, colB2 = obB2 & 63;

  auto STAGE = [&](int t) {
    int s = t & 3;
    int k0 = t * 32;
    gload16((const char*)Ab + ((size_t)(m0 + rowA) * NIN + k0) * 2 + colA,
            (char*)&lA[s][0] + obA);
    gload16((const char*)Bb + ((size_t)(n0 + rowB1) * NIN + k0) * 2 + colB1,
            (char*)&lB[s][0] + obB1);
    gload16((const char*)Bb + ((size_t)(n0 + rowB2) * NIN + k0) * 2 + colB2,
            (char*)&lB[s][0] + obB2);
  };

  f32x4 acc[2][4] = {};

  auto COMPUTE = [&](int t) {
    int s = t & 3;
    bf16x8 aF[2], bF[4];
#pragma unroll
    for (int m = 0; m < 2; ++m)
      aF[m] = *(const bf16x8*)&lA[s][(wr * 32 + m * 16 + fr) * 32 + kq * 8];
#pragma unroll
    for (int n = 0; n < 4; ++n)
      bF[n] = *(const bf16x8*)&lB[s][(wc * 64 + n * 16 + fr) * 32 + kq * 8];
#pragma unroll
    for (int m = 0; m < 2; ++m)
#pragma unroll
      for (int n = 0; n < 4; ++n)
        acc[m][n] = __builtin_amdgcn_mfma_f32_16x16x32_bf16(aF[m], bF[n], acc[m][n], 0, 0, 0);
  };

  // prologue: 4 tiles in flight (12 loads)
  STAGE(0); STAGE(1); STAGE(2); STAGE(3);
  for (int i = 0; i < 10; ++i) {
    PRE_BAR(6);                   // tiles 2i,2i+1 landed (2 tiles = 6 loads in flight)
    COMPUTE(2 * i); COMPUTE(2 * i + 1);
    POST_BAR();
    STAGE(2 * i + 4); STAGE(2 * i + 5);
  }
  PRE_BAR(6);  COMPUTE(20); COMPUTE(21);  POST_BAR();
  PRE_BAR(0);  COMPUTE(22); COMPUTE(23);

  float* Cb = C + (size_t)b * NS * NOUT;
#pragma unroll
  for (int m = 0; m < 2; ++m) {
    int rb = m0 + wr * 32 + m * 16 + kq * 4;
#pragma unroll
    for (int n = 0; n < 4; ++n) {
      int col = n0 + wc * 64 + n * 16 + fr;
#pragma unroll
      for (int r = 0; r < 4; ++r)
        Cb[(size_t)(rb + r) * NOUT + col] = acc[m][n][r];
    }
  }
}

// ---------------- K5: ew = bf16(res + 0.9*sum_e g*rtw) + loss ----------------
__global__ __launch_bounds__(256) void k_combine(const u16* __restrict__ rtwb,
                                                 const float* __restrict__ res,
                                                 const float* __restrict__ g,
                                                 u16* __restrict__ ew,
                                                 float* __restrict__ loss_out) {
  __shared__ float gs[NB * NE];
  int tid = threadIdx.x;
  if (tid < NB * NE) gs[tid] = 0.9f * g[tid];
  __syncthreads();
  if (blockIdx.x == 0 && tid == 0) {
    float imp[NE], ld[NE];
    for (int e = 0; e < NE; ++e) {
      float si = 0.f, sl = 0.f;
      for (int b = 0; b < NB; ++b) {
        float gg = g[b * NE + e];
        si += gg; sl += (gg > 0.f) ? 1.f : 0.f;
      }
      imp[e] = si; ld[e] = sl;
    }
    float loss = 0.f;
    for (int which = 0; which < 2; ++which) {
      const float* a = which ? ld : imp;
      float mean = 0.f;
      for (int e = 0; e < NE; ++e) mean += a[e];
      mean *= (1.0f / NE);
      float var = 0.f;
      for (int e = 0; e < NE; ++e) { float d = a[e] - mean; var += d * d; }
      var *= (1.0f / (NE - 1));
      loss += var / (mean * mean + 1e-10f);
    }
    loss_out[0] = 0.01f * loss;
  }
  size_t base = ((size_t)blockIdx.x * 256 + tid) * 8;
  float rv[NE][8];
#pragma unroll
  for (int e = 0; e < NE; ++e) {
    bf16x8 v = *(const bf16x8*)(rtwb + (size_t)e * EWN + base);
#pragma unroll
    for (int j = 0; j < 8; ++j) rv[e][j] = bf2f((u16)v[j]);
  }
  float r8[8];
  {
    float4 ra = *(const float4*)(res + base);
    float4 rb = *(const float4*)(res + base + 4);
    r8[0] = ra.x; r8[1] = ra.y; r8[2] = ra.z; r8[3] = ra.w;
    r8[4] = rb.x; r8[5] = rb.y; r8[6] = rb.z; r8[7] = rb.w;
  }
  for (int b = 0; b < NB; ++b) {
    float a[8];
#pragma unroll
    for (int j = 0; j < 8; ++j) a[j] = r8[j];
#pragma unroll
    for (int e = 0; e < NE; ++e) {
      float gg = gs[b * NE + e];
#pragma unroll
      for (int j = 0; j < 8; ++j) a[j] += gg * rv[e][j];
    }
    bf16x8 o;
#pragma unroll
    for (int j = 0; j < 8; ++j) o[j] = (short)f2bf(a[j]);
    *(bf16x8*)(ew + (size_t)b * EWN + base) = o;
  }
}

extern "C" void kernel_launch(void* const* d_in, const int* in_sizes, int n_in,
                              void* d_out, int out_size, void* d_ws, size_t ws_size,
                              hipStream_t stream) {
  const float* x = (const float*)d_in[0];
  const float* w_gate = (const float*)d_in[1];
  const float* weight = (const float*)d_in[2];
  const float* res_w = (const float*)d_in[3];
  const float* c1i = (const float*)d_in[4];
  const float* c2i = (const float*)d_in[5];
  const float* c1o = (const float*)d_in[6];
  const float* c2o = (const float*)d_in[7];

  char* ws = (char*)d_ws;
  float* part = (float*)(ws + OFF_PART);
  float* gates = (float*)(ws + OFF_GATES);
  u16* xbf = (u16*)(ws + OFF_XBF);
  u16* Wd = (u16*)(ws + OFF_WD);
  u16* T1t = (u16*)(ws + OFF_T1T);
  u16* rtwb = (u16*)(ws + OFF_RTW);
  u16* ew = (u16*)(ws + OFF_EW);

  float* y = (float*)d_out;
  float* loss = y + YSZ;

  // 1) mean partials + x->bf16 (blocks 0..1023) and Wd (blocks 1024..3327)
  k_xm_wd<<<dim3(3328), 256, 0, stream>>>(x, part, xbf, weight, res_w, Wd);
  // 2) pass A: T1t[e][i][jk] = sum_lm (c1i⊗c2i)[i][lm] * Wd[e][jk][lm]
  //    + folded gating (blocks 576..591)
  gemm_kron<<<dim3(592), 256, 0, stream>>>(c1i, c2i, Wd, T1t, part, w_gate, gates);
  // 3) pass B: rtw[e][o][i] = sum_jk (c1o⊗c2o)[o][jk] * T1t[e][i][jk]
  gemm_kron<<<dim3(576), 256, 0, stream>>>(c1o, c2o, T1t, rtwb, nullptr, nullptr, nullptr);
  // 4) combine into per-batch expert weights (bf16) + loss
  k_combine<<<dim3(288), 256, 0, stream>>>(rtwb, res_w, gates, ew, loss);
  // 5) main grouped GEMM
  gemm_main<<<dim3(768), 256, 0, stream>>>(xbf, ew, y);
}